// Round 8
// baseline (4113.101 us; speedup 1.0000x reference)
//
#include <hip/hip_runtime.h>
#include <hip/hip_bf16.h>

// Problem constants
#define BB 64
#define TT 256
#define HH 512
#define EE 256
#define NTAGS 50
#define BT (BB * TT)  // 16384

typedef _Float16 f16;
typedef __attribute__((ext_vector_type(2))) _Float16 half2v;
typedef __attribute__((ext_vector_type(4))) _Float16 half4;
typedef __attribute__((ext_vector_type(8))) _Float16 half8;
typedef __attribute__((ext_vector_type(8))) short short8;
typedef __attribute__((ext_vector_type(4))) float f32x4;
typedef __hip_bfloat16 bf16;

__device__ __forceinline__ float sigm(float x) {
    return 1.f / (1.f + __expf(-x));
}
__device__ __forceinline__ float tanh_f(float x) {
    float ax = fabsf(x);
    float e = __expf(2.f * ax);
    float t = 1.f - 2.f / (e + 1.f);
    return x < 0.f ? -t : t;
}
__device__ __forceinline__ short f2bs(float f) {
    return (short)__bfloat16_as_ushort(__float2bfloat16(f));
}
// split 8 fp32 values (in regs) into bf16 hi + bf16 lo(residual)
__device__ __forceinline__ void split8v(const float* vv, bf16* hi, bf16* lo) {
    short8 h8, l8;
#pragma unroll
    for (int j = 0; j < 8; ++j) {
        bf16 h = __float2bfloat16(vv[j]);
        h8[j] = (short)__bfloat16_as_ushort(h);
        l8[j] = f2bs(vv[j] - __bfloat162float(h));
    }
    *(short8*)hi = h8;
    *(short8*)lo = l8;
}
__device__ __forceinline__ void split8(const float* p, bf16* hi, bf16* lo) {
    float4 v0 = *(const float4*)p;
    float4 v1 = *(const float4*)(p + 4);
    float vv[8] = {v0.x, v0.y, v0.z, v0.w, v1.x, v1.y, v1.z, v1.w};
    split8v(vv, hi, lo);
}
__device__ __forceinline__ void split8h(const f16* p, bf16* hi, bf16* lo) {
    half8 a = *(const half8*)p;
    float vv[8];
#pragma unroll
    for (int j = 0; j < 8; ++j) vv[j] = (float)a[j];
    split8v(vv, hi, lo);
}

// ---------------------------------------------------------------------------
// 2 dirs x 64 PACKED flags (4B each, 256B/dir) at dir*1024 ints; zero 8KB
__global__ void bar_init(int* __restrict__ bar) {
    bar[blockIdx.x * 256 + threadIdx.x] = 0;
}

// ---------------------------------------------------------------------------
// embedding gather fp32 -> f16 storage
__global__ __launch_bounds__(256) void embed_gather(
    const int* __restrict__ x, const float* __restrict__ emb, f16* __restrict__ e) {
    int idx = blockIdx.x * 4 + (threadIdx.x >> 6);
    int lane = threadIdx.x & 63;
    int tok = x[idx];
    float4 v = *(const float4*)(emb + (size_t)tok * EE + lane * 4);
    half4 o;
    o[0] = (f16)v.x; o[1] = (f16)v.y; o[2] = (f16)v.z; o[3] = (f16)v.w;
    *(half4*)(e + (size_t)idx * EE + lane * 4) = o;
}

// ---------------------------------------------------------------------------
// C[M,N] = A[M,K] @ W[N,K]^T + bias[N].  A: f16 storage, W/bias fp32.
// Both split to bf16 hi+lo in LDS; 3 MFMA products -> ~fp32 accuracy. f16 out.
__global__ __launch_bounds__(256) void gemm_bt(
    const f16* __restrict__ A, const float* __restrict__ W,
    const float* __restrict__ bias, f16* __restrict__ C,
    int M, int N, int K) {
    __shared__ bf16 Ah[128][72], Al[128][72];
    __shared__ bf16 Wh[128][72], Wl[128][72];
    const int m0 = blockIdx.x * 128;
    const int n0 = blockIdx.y * 128;
    const int tid = threadIdx.x;
    const int wave = tid >> 6;
    const int lane = tid & 63;
    const int lrow = lane & 15;
    const int quad = lane >> 4;
    const int msub = (wave >> 1) * 64;
    const int nsub = (wave & 1) * 64;

    f32x4 acc[4][4];
#pragma unroll
    for (int i = 0; i < 4; ++i)
#pragma unroll
        for (int j = 0; j < 4; ++j) acc[i][j] = (f32x4){0.f, 0.f, 0.f, 0.f};

    for (int k0 = 0; k0 < K; k0 += 64) {
        __syncthreads();
#pragma unroll
        for (int c = 0; c < 4; ++c) {
            int f = c * 256 + tid;
            int row = f >> 3;
            int kc = f & 7;
            split8h(A + (size_t)(m0 + row) * K + k0 + kc * 8,
                    &Ah[row][kc * 8], &Al[row][kc * 8]);
            split8(W + (size_t)(n0 + row) * K + k0 + kc * 8,
                   &Wh[row][kc * 8], &Wl[row][kc * 8]);
        }
        __syncthreads();
#pragma unroll
        for (int ks = 0; ks < 2; ++ks) {
            short8 ah[4], al[4], bh[4], bl[4];
#pragma unroll
            for (int i = 0; i < 4; ++i) {
                ah[i] = *(const short8*)&Ah[msub + i * 16 + lrow][ks * 32 + quad * 8];
                al[i] = *(const short8*)&Al[msub + i * 16 + lrow][ks * 32 + quad * 8];
            }
#pragma unroll
            for (int j = 0; j < 4; ++j) {
                bh[j] = *(const short8*)&Wh[nsub + j * 16 + lrow][ks * 32 + quad * 8];
                bl[j] = *(const short8*)&Wl[nsub + j * 16 + lrow][ks * 32 + quad * 8];
            }
#pragma unroll
            for (int i = 0; i < 4; ++i)
#pragma unroll
                for (int j = 0; j < 4; ++j) {
                    acc[i][j] = __builtin_amdgcn_mfma_f32_16x16x32_bf16(ah[i], bh[j], acc[i][j], 0, 0, 0);
                    acc[i][j] = __builtin_amdgcn_mfma_f32_16x16x32_bf16(ah[i], bl[j], acc[i][j], 0, 0, 0);
                    acc[i][j] = __builtin_amdgcn_mfma_f32_16x16x32_bf16(al[i], bh[j], acc[i][j], 0, 0, 0);
                }
        }
    }

#pragma unroll
    for (int j = 0; j < 4; ++j) {
        int n = n0 + nsub + j * 16 + lrow;
        float bv = bias[n];
#pragma unroll
        for (int i = 0; i < 4; ++i)
#pragma unroll
            for (int r = 0; r < 4; ++r) {
                int m = m0 + msub + i * 16 + quad * 4 + r;
                C[(size_t)m * N + n] = (f16)(acc[i][j][r] + bv);
            }
    }
}

// ---------------------------------------------------------------------------
// Classifier: logits[BT,50] fp32 = out2[BT,1024] @ cls_w[50,1024]^T + cls_b.
__global__ __launch_bounds__(256) void cls_gemm(
    const f16* __restrict__ A, const float* __restrict__ W,
    const float* __restrict__ bias, float* __restrict__ C) {
    __shared__ bf16 Ah[128][72], Al[128][72];
    __shared__ bf16 Wh[64][72], Wl[64][72];
    const int m0 = blockIdx.x * 128;
    const int tid = threadIdx.x;
    const int wave = tid >> 6;
    const int lane = tid & 63;
    const int lrow = lane & 15;
    const int quad = lane >> 4;
    const int msub = wave * 32;

    f32x4 acc[2][4];
#pragma unroll
    for (int i = 0; i < 2; ++i)
#pragma unroll
        for (int j = 0; j < 4; ++j) acc[i][j] = (f32x4){0.f, 0.f, 0.f, 0.f};

    for (int k0 = 0; k0 < 1024; k0 += 64) {
        __syncthreads();
#pragma unroll
        for (int c = 0; c < 4; ++c) {
            int f = c * 256 + tid;
            int row = f >> 3;
            int kc = f & 7;
            split8h(A + (size_t)(m0 + row) * 1024 + k0 + kc * 8,
                    &Ah[row][kc * 8], &Al[row][kc * 8]);
        }
#pragma unroll
        for (int c = 0; c < 2; ++c) {
            int f = c * 256 + tid;
            int row = f >> 3;
            int kc = f & 7;
            int wr = row < NTAGS ? row : NTAGS - 1;
            split8(W + (size_t)wr * 1024 + k0 + kc * 8,
                   &Wh[row][kc * 8], &Wl[row][kc * 8]);
        }
        __syncthreads();
#pragma unroll
        for (int ks = 0; ks < 2; ++ks) {
            short8 ah[2], al[2], bh[4], bl[4];
#pragma unroll
            for (int i = 0; i < 2; ++i) {
                ah[i] = *(const short8*)&Ah[msub + i * 16 + lrow][ks * 32 + quad * 8];
                al[i] = *(const short8*)&Al[msub + i * 16 + lrow][ks * 32 + quad * 8];
            }
#pragma unroll
            for (int j = 0; j < 4; ++j) {
                bh[j] = *(const short8*)&Wh[j * 16 + lrow][ks * 32 + quad * 8];
                bl[j] = *(const short8*)&Wl[j * 16 + lrow][ks * 32 + quad * 8];
            }
#pragma unroll
            for (int i = 0; i < 2; ++i)
#pragma unroll
                for (int j = 0; j < 4; ++j) {
                    acc[i][j] = __builtin_amdgcn_mfma_f32_16x16x32_bf16(ah[i], bh[j], acc[i][j], 0, 0, 0);
                    acc[i][j] = __builtin_amdgcn_mfma_f32_16x16x32_bf16(ah[i], bl[j], acc[i][j], 0, 0, 0);
                    acc[i][j] = __builtin_amdgcn_mfma_f32_16x16x32_bf16(al[i], bh[j], acc[i][j], 0, 0, 0);
                }
        }
    }

#pragma unroll
    for (int j = 0; j < 4; ++j) {
        int n = j * 16 + lrow;
        if (n < NTAGS) {
            float bv = bias[n];
#pragma unroll
            for (int i = 0; i < 2; ++i)
#pragma unroll
                for (int r = 0; r < 4; ++r) {
                    int m = m0 + msub + i * 16 + quad * 4 + r;
                    C[(size_t)m * NTAGS + n] = acc[i][j][r] + bv;
                }
        }
    }
}

// ---------------------------------------------------------------------------
// Persistent masked BiLSTM scan — EXACT R5 structure (verified, 4001us)
// with ONE delta: PACKED flags.
//
// Packed flags: 64 flags x 4B contiguous per dir (was 64B-spaced).  Wave0's
// poll becomes ONE coalesced 4-line load per iteration instead of a 64-line
// gather -> 64x fewer poll transactions on the LLC fabric that also carries
// producer flag stores and the h-bursts.  Safe: flags are single-producer
// monotonic plain atomic stores (no RMW since R3), so line sharing costs
// nothing; protocol, barriers, drains, data path are byte-identical to R5.
//
// (R6 fence-broadcast and R7 arrive-counter experiments shelved after two
// container failures; this round re-anchors on the verified protocol.)
__global__ __launch_bounds__(256, 1) void lstm_scan(
    const f16* __restrict__ xpre_f, const f16* __restrict__ xpre_b,
    const float* __restrict__ whh_f, const float* __restrict__ whh_b,
    const int* __restrict__ lengths,
    f16* __restrict__ out,      // [BT, 2H]
    bf16* __restrict__ hbuf,    // [dir][parity][hi/lo][64][512]
    int* __restrict__ bar, int base) {
    __shared__ bf16 w_lo2[32][64][8];  // [slot=nt*16+c][lane][8] : lane-private
    __shared__ float gat[64][33];      // [batch][gate*8+u], stride 33
    __shared__ int len_s[64];

    const int dir = blockIdx.x >> 6;
    const int sl = blockIdx.x & 63;
    const int tid = threadIdx.x;
    const int wave = tid >> 6;
    const int lane = tid & 63;
    const int lrow = lane & 15;
    const int quad = lane >> 4;
    // wave-local gate mapping: thread -> (batch gb in wave's 16, unit-pair)
    const int gb = wave * 16 + (lane >> 2);
    const int up = lane & 3;
    const int u0 = up * 2;

    const f16* xpre = dir ? xpre_b : xpre_f;
    const float* whh = dir ? whh_b : whh_f;
    bf16* hb = hbuf + (size_t)dir * 2 * 2 * BB * HH;
    int* flags = bar + dir * 1024;   // 64 PACKED monotonic flags (256B)
    int* myflag = flags + sl;

    // ---- stage w_hh slice: hi -> regs BH[nt][c], lo -> lane-private LDS.
    // B-frag for (nt,c): w row R=nt*16+lrow (gate g=R>>3, unit u=R&7),
    // k-cols c*32+quad*8..+8  <-  whh[(g*512 + sl*8 + u)][k]
    short8 BH[2][16];
#pragma unroll
    for (int nt = 0; nt < 2; ++nt) {
        int R = nt * 16 + lrow;
        const float* wr = whh + (size_t)((R >> 3) * HH + sl * 8 + (R & 7)) * HH + quad * 8;
#pragma unroll
        for (int c = 0; c < 16; ++c) {
            float4 v0 = *(const float4*)(wr + c * 32);
            float4 v1 = *(const float4*)(wr + c * 32 + 4);
            float vv[8] = {v0.x, v0.y, v0.z, v0.w, v1.x, v1.y, v1.z, v1.w};
            short8 h8, l8;
#pragma unroll
            for (int j = 0; j < 8; ++j) {
                bf16 h = __float2bfloat16(vv[j]);
                h8[j] = (short)__bfloat16_as_ushort(h);
                l8[j] = f2bs(vv[j] - __bfloat162float(h));
            }
            BH[nt][c] = h8;
            *(short8*)&w_lo2[nt * 16 + c][lane][0] = l8;
        }
    }
    if (tid < 64) len_s[tid] = lengths[tid];
    __syncthreads();

    // persistent per-thread recurrent state (2 hidden units each)
    float hr0 = 0.f, hr1 = 0.f, cr0 = 0.f, cr1 = 0.f;

    // prefetch xpre for s = 0 (len >= 1 always)
    float pr[2][4];
    {
        int len = len_s[gb];
        int ta = dir ? (len - 1) : 0;
        const f16* xp = xpre + (size_t)(gb * TT + ta) * 2048 + sl * 8 + u0;
        half2v g0 = *(const half2v*)(xp);
        half2v g1 = *(const half2v*)(xp + 512);
        half2v g2 = *(const half2v*)(xp + 1024);
        half2v g3 = *(const half2v*)(xp + 1536);
        pr[0][0] = (float)g0[0]; pr[1][0] = (float)g0[1];
        pr[0][1] = (float)g1[0]; pr[1][1] = (float)g1[1];
        pr[0][2] = (float)g2[0]; pr[1][2] = (float)g2[1];
        pr[0][3] = (float)g3[0]; pr[1][3] = (float)g3[1];
    }

    for (int s = 0; s < TT; ++s) {
        if (s > 0) {
            const int target = base + s;

            // ---- wave0-only readiness poll: ONE coalesced load of the 64
            // packed flags per iteration (lane L watches flags[L])
            if (wave == 0) {
                int* fp = &flags[lane];
                int v = __hip_atomic_load(fp, __ATOMIC_RELAXED,
                                          __HIP_MEMORY_SCOPE_AGENT);
                while (__ballot(v >= target) != ~0ull) {
                    __builtin_amdgcn_s_sleep(1);
                    v = __hip_atomic_load(fp, __ATOMIC_RELAXED,
                                          __HIP_MEMORY_SCOPE_AGENT);
                }
            }
            __syncthreads();
            __asm__ volatile("" ::: "memory");

            // ---- burst-issue ALL h loads: 32 x dwordx4, sc0 sc1
            const int b = wave * 16 + lrow;
            const char* hpb = (const char*)hb +
                (size_t)(((s & 1) ^ 1) * 2) * BB * HH * sizeof(bf16);
            const char* hib = hpb + b * 1024 + quad * 16;
            const char* lob = hib + BB * HH * sizeof(bf16);  // +64KB

            short8 AH[16], AL[16];
#pragma unroll
            for (int c = 0; c < 16; ++c) {
                asm volatile("global_load_dwordx4 %0, %1, off offset:%2 sc0 sc1"
                             : "=v"(AH[c]) : "v"(hib), "n"(c * 64));
                asm volatile("global_load_dwordx4 %0, %1, off offset:%2 sc0 sc1"
                             : "=v"(AL[c]) : "v"(lob), "n"(c * 64));
            }

            // 4 accumulator chains: (nt, c&1)
            f32x4 ac[2][2];
            ac[0][0] = (f32x4){0.f, 0.f, 0.f, 0.f};
            ac[0][1] = (f32x4){0.f, 0.f, 0.f, 0.f};
            ac[1][0] = (f32x4){0.f, 0.f, 0.f, 0.f};
            ac[1][1] = (f32x4){0.f, 0.f, 0.f, 0.f};

            // first half ready at vmcnt(16) (in-order completion counting)
            asm volatile("s_waitcnt vmcnt(16)" ::: "memory");
            __builtin_amdgcn_sched_barrier(0);
#pragma unroll
            for (int c = 0; c < 8; ++c) {
#pragma unroll
                for (int nt = 0; nt < 2; ++nt) {
                    short8 bll = *(const short8*)&w_lo2[nt * 16 + c][lane][0];
                    ac[nt][c & 1] = __builtin_amdgcn_mfma_f32_16x16x32_bf16(AH[c], BH[nt][c], ac[nt][c & 1], 0, 0, 0);
                    ac[nt][c & 1] = __builtin_amdgcn_mfma_f32_16x16x32_bf16(AL[c], BH[nt][c], ac[nt][c & 1], 0, 0, 0);
                    ac[nt][c & 1] = __builtin_amdgcn_mfma_f32_16x16x32_bf16(AH[c], bll, ac[nt][c & 1], 0, 0, 0);
                }
            }
            asm volatile("s_waitcnt vmcnt(0)" ::: "memory");
            __builtin_amdgcn_sched_barrier(0);
#pragma unroll
            for (int c = 8; c < 16; ++c) {
#pragma unroll
                for (int nt = 0; nt < 2; ++nt) {
                    short8 bll = *(const short8*)&w_lo2[nt * 16 + c][lane][0];
                    ac[nt][c & 1] = __builtin_amdgcn_mfma_f32_16x16x32_bf16(AH[c], BH[nt][c], ac[nt][c & 1], 0, 0, 0);
                    ac[nt][c & 1] = __builtin_amdgcn_mfma_f32_16x16x32_bf16(AL[c], BH[nt][c], ac[nt][c & 1], 0, 0, 0);
                    ac[nt][c & 1] = __builtin_amdgcn_mfma_f32_16x16x32_bf16(AH[c], bll, ac[nt][c & 1], 0, 0, 0);
                }
            }
            // acc -> gat (wave-local rows only); no block barrier needed:
            // each wave reads back only rows it wrote (rule #18 fence).
#pragma unroll
            for (int nt = 0; nt < 2; ++nt)
#pragma unroll
                for (int r = 0; r < 4; ++r)
                    gat[wave * 16 + quad * 4 + r][nt * 16 + lrow] =
                        ac[nt][0][r] + ac[nt][1][r];
            asm volatile("s_waitcnt lgkmcnt(0)" ::: "memory");
            __builtin_amdgcn_sched_barrier(0);
        }

        // ---- gate phase: thread handles (gb, units u0,u0+1), wave-local ----
        const int len = len_s[gb];
        const bool act = (s < len);
        if (act) {
            float z0[4], z1[4];
#pragma unroll
            for (int g = 0; g < 4; ++g) { z0[g] = pr[0][g]; z1[g] = pr[1][g]; }
            if (s > 0) {
#pragma unroll
                for (int g = 0; g < 4; ++g) {
                    z0[g] += gat[gb][g * 8 + u0];
                    z1[g] += gat[gb][g * 8 + u0 + 1];
                }
            }
            float i0 = sigm(z0[0]), f0 = sigm(z0[1]);
            float g0 = tanh_f(z0[2]), o0 = sigm(z0[3]);
            float i1 = sigm(z1[0]), f1 = sigm(z1[1]);
            float g1 = tanh_f(z1[2]), o1 = sigm(z1[3]);
            cr0 = f0 * cr0 + i0 * g0;
            cr1 = f1 * cr1 + i1 * g1;
            hr0 = o0 * tanh_f(cr0);
            hr1 = o1 * tanh_f(cr1);
        }
        // publish hi/lo packed (always; carried h for masked rows): 4B sc0sc1
        {
            bf16 bh0 = __float2bfloat16(hr0);
            bf16 bh1 = __float2bfloat16(hr1);
            unsigned int hw = (unsigned int)__bfloat16_as_ushort(bh0) |
                              ((unsigned int)__bfloat16_as_ushort(bh1) << 16);
            float r0 = hr0 - __bfloat162float(bh0);
            float r1 = hr1 - __bfloat162float(bh1);
            unsigned int lw = (unsigned int)(unsigned short)f2bs(r0) |
                              ((unsigned int)(unsigned short)f2bs(r1) << 16);
            char* hcb = (char*)hb + (size_t)((s & 1) * 2) * BB * HH * sizeof(bf16);
            char* pa = hcb + gb * 1024 + (sl * 8 + u0) * 2;
            char* pb = pa + BB * HH * sizeof(bf16);
            asm volatile("global_store_dword %0, %1, off sc0 sc1"
                         :: "v"(pa), "v"(hw) : "memory");
            asm volatile("global_store_dword %0, %1, off sc0 sc1"
                         :: "v"(pb), "v"(lw) : "memory");
        }
        asm volatile("s_waitcnt vmcnt(0)" ::: "memory");  // drain h-stores
        __syncthreads();

        // signal: one fire-and-forget monotonic atomic STORE per block
        if (tid == 0)
            __hip_atomic_store(myflag, base + s + 1, __ATOMIC_RELAXED,
                               __HIP_MEMORY_SCOPE_AGENT);

        // off the inter-block critical path: prefetch next xpre, then out store
        if (s + 1 < TT) {
            if (s + 1 < len) {
                int ta = dir ? (len - 2 - s) : (s + 1);
                const f16* xp = xpre + (size_t)(gb * TT + ta) * 2048 + sl * 8 + u0;
                half2v g0 = *(const half2v*)(xp);
                half2v g1 = *(const half2v*)(xp + 512);
                half2v g2 = *(const half2v*)(xp + 1024);
                half2v g3 = *(const half2v*)(xp + 1536);
                pr[0][0] = (float)g0[0]; pr[1][0] = (float)g0[1];
                pr[0][1] = (float)g1[0]; pr[1][1] = (float)g1[1];
                pr[0][2] = (float)g2[0]; pr[1][2] = (float)g2[1];
                pr[0][3] = (float)g3[0]; pr[1][3] = (float)g3[1];
            }
        }
        if (act) {
            int ta = dir ? (len - 1 - s) : s;
            half2v ov; ov[0] = (f16)hr0; ov[1] = (f16)hr1;
            *(half2v*)(out + (size_t)(gb * TT + ta) * 1024 + dir * 512 + sl * 8 + u0) = ov;
        } else {
            half2v zv; zv[0] = (f16)0.f; zv[1] = (f16)0.f;
            *(half2v*)(out + (size_t)(gb * TT + s) * 1024 + dir * 512 + sl * 8 + u0) = zv;
        }
    }
}

// ---------------------------------------------------------------------------
extern "C" void kernel_launch(void* const* d_in, const int* in_sizes, int n_in,
                              void* d_out, int out_size, void* d_ws, size_t ws_size,
                              hipStream_t stream) {
    const int* x = (const int*)d_in[0];
    const int* lengths = (const int*)d_in[1];
    const float* emb = (const float*)d_in[2];
    const float* w_ih_f1 = (const float*)d_in[3];
    const float* w_hh_f1 = (const float*)d_in[4];
    const float* b_f1 = (const float*)d_in[5];
    const float* w_ih_b1 = (const float*)d_in[6];
    const float* w_hh_b1 = (const float*)d_in[7];
    const float* b_b1 = (const float*)d_in[8];
    const float* w_ih_f2 = (const float*)d_in[9];
    const float* w_hh_f2 = (const float*)d_in[10];
    const float* b_f2 = (const float*)d_in[11];
    const float* w_ih_b2 = (const float*)d_in[12];
    const float* w_hh_b2 = (const float*)d_in[13];
    const float* b_b2 = (const float*)d_in[14];
    const float* cls_w = (const float*)d_in[15];
    const float* cls_b = (const float*)d_in[16];
    float* logits = (float*)d_out;

    // workspace layout (bytes) — max touched offset ~176 MB (proven envelope)
    char* ws = (char*)d_ws;
    int* bar = (int*)ws;                        // 0 .. 8 KB (2 dirs, packed flags)
    bf16* hbuf = (bf16*)(ws + 16384);           // 16 KB .. ~1.06 MB
    f16* e = (f16*)(ws + 2097152);              // 2 MB .. 10 MB
    f16* xpre_f = (f16*)(ws + 16777216);        // 16 MB .. 80 MB
    f16* xpre_b = (f16*)(ws + 83886080);        // 80 MB .. 144 MB
    f16* out1 = (f16*)(ws + 150994944);         // 144 MB .. 176 MB
    f16* out2 = out1;  // alias: out1 dead once layer-2 GEMMs complete

    bar_init<<<8, 256, 0, stream>>>(bar);
    embed_gather<<<BT / 4, 256, 0, stream>>>(x, emb, e);

    dim3 g1(BT / 128, 2048 / 128);
    gemm_bt<<<g1, 256, 0, stream>>>(e, w_ih_f1, b_f1, xpre_f, BT, 2048, EE);
    gemm_bt<<<g1, 256, 0, stream>>>(e, w_ih_b1, b_b1, xpre_b, BT, 2048, EE);
    lstm_scan<<<128, 256, 0, stream>>>(xpre_f, xpre_b, w_hh_f1, w_hh_b1,
                                       lengths, out1, hbuf, bar, 0);

    gemm_bt<<<g1, 256, 0, stream>>>(out1, w_ih_f2, b_f2, xpre_f, BT, 2048, 2 * HH);
    gemm_bt<<<g1, 256, 0, stream>>>(out1, w_ih_b2, b_b2, xpre_b, BT, 2048, 2 * HH);
    lstm_scan<<<128, 256, 0, stream>>>(xpre_f, xpre_b, w_hh_f2, w_hh_b2,
                                       lengths, out2, hbuf, bar, TT);

    cls_gemm<<<BT / 128, 256, 0, stream>>>(out2, cls_w, cls_b, logits);
}

// Round 9
// 4091.073 us; speedup vs baseline: 1.0054x; 1.0054x over previous
//
#include <hip/hip_runtime.h>
#include <hip/hip_bf16.h>

// Problem constants
#define BB 64
#define TT 256
#define HH 512
#define EE 256
#define NTAGS 50
#define BT (BB * TT)  // 16384

typedef _Float16 f16;
typedef __attribute__((ext_vector_type(2))) _Float16 half2v;
typedef __attribute__((ext_vector_type(4))) _Float16 half4;
typedef __attribute__((ext_vector_type(8))) _Float16 half8;
typedef __attribute__((ext_vector_type(8))) short short8;
typedef __attribute__((ext_vector_type(4))) float f32x4;
typedef __hip_bfloat16 bf16;

__device__ __forceinline__ float sigm(float x) {
    return 1.f / (1.f + __expf(-x));
}
__device__ __forceinline__ float tanh_f(float x) {
    float ax = fabsf(x);
    float e = __expf(2.f * ax);
    float t = 1.f - 2.f / (e + 1.f);
    return x < 0.f ? -t : t;
}
__device__ __forceinline__ short f2bs(float f) {
    return (short)__bfloat16_as_ushort(__float2bfloat16(f));
}
// split 8 fp32 values (in regs) into bf16 hi + bf16 lo(residual)
__device__ __forceinline__ void split8v(const float* vv, bf16* hi, bf16* lo) {
    short8 h8, l8;
#pragma unroll
    for (int j = 0; j < 8; ++j) {
        bf16 h = __float2bfloat16(vv[j]);
        h8[j] = (short)__bfloat16_as_ushort(h);
        l8[j] = f2bs(vv[j] - __bfloat162float(h));
    }
    *(short8*)hi = h8;
    *(short8*)lo = l8;
}
__device__ __forceinline__ void split8(const float* p, bf16* hi, bf16* lo) {
    float4 v0 = *(const float4*)p;
    float4 v1 = *(const float4*)(p + 4);
    float vv[8] = {v0.x, v0.y, v0.z, v0.w, v1.x, v1.y, v1.z, v1.w};
    split8v(vv, hi, lo);
}
__device__ __forceinline__ void split8h(const f16* p, bf16* hi, bf16* lo) {
    half8 a = *(const half8*)p;
    float vv[8];
#pragma unroll
    for (int j = 0; j < 8; ++j) vv[j] = (float)a[j];
    split8v(vv, hi, lo);
}

// ---------------------------------------------------------------------------
// 2 dirs x 64 flags x 16-int (64B) spacing = 2048 ints = 8KB (R5-verified)
__global__ void bar_init(int* __restrict__ bar) {
    bar[blockIdx.x * 256 + threadIdx.x] = 0;
}

// ---------------------------------------------------------------------------
// One-time weight split: fp32 W -> planar bf16 hi + lo.  Removes the
// per-tile redundant split8 work from the GEMMs (W rows were re-split
// M/128 = 128 times per GEMM).
__global__ __launch_bounds__(256) void split_w(
    const float* __restrict__ W, bf16* __restrict__ hi, bf16* __restrict__ lo,
    int total8) {
    int i = blockIdx.x * 256 + threadIdx.x;
    if (i < total8)
        split8(W + (size_t)i * 8, hi + (size_t)i * 8, lo + (size_t)i * 8);
}

// ---------------------------------------------------------------------------
// embedding gather fp32 -> f16 storage
__global__ __launch_bounds__(256) void embed_gather(
    const int* __restrict__ x, const float* __restrict__ emb, f16* __restrict__ e) {
    int idx = blockIdx.x * 4 + (threadIdx.x >> 6);
    int lane = threadIdx.x & 63;
    int tok = x[idx];
    float4 v = *(const float4*)(emb + (size_t)tok * EE + lane * 4);
    half4 o;
    o[0] = (f16)v.x; o[1] = (f16)v.y; o[2] = (f16)v.z; o[3] = (f16)v.w;
    *(half4*)(e + (size_t)idx * EE + lane * 4) = o;
}

// ---------------------------------------------------------------------------
// C[M,N] = A[M,K] @ W[N,K]^T + bias[N].  A: f16 (split to hi/lo on the fly);
// W: PRE-SPLIT planar bf16 hi/lo (pure vector-copy staging).  3 MFMA
// products -> ~fp32 accuracy.  f16 out.
__global__ __launch_bounds__(256) void gemm_bt2(
    const f16* __restrict__ A, const bf16* __restrict__ whi,
    const bf16* __restrict__ wlo, const float* __restrict__ bias,
    f16* __restrict__ C, int M, int N, int K) {
    __shared__ bf16 Ah[128][72], Al[128][72];
    __shared__ bf16 Wh[128][72], Wl[128][72];
    const int m0 = blockIdx.x * 128;
    const int n0 = blockIdx.y * 128;
    const int tid = threadIdx.x;
    const int wave = tid >> 6;
    const int lane = tid & 63;
    const int lrow = lane & 15;
    const int quad = lane >> 4;
    const int msub = (wave >> 1) * 64;
    const int nsub = (wave & 1) * 64;

    f32x4 acc[4][4];
#pragma unroll
    for (int i = 0; i < 4; ++i)
#pragma unroll
        for (int j = 0; j < 4; ++j) acc[i][j] = (f32x4){0.f, 0.f, 0.f, 0.f};

    for (int k0 = 0; k0 < K; k0 += 64) {
        __syncthreads();
#pragma unroll
        for (int c = 0; c < 4; ++c) {
            int f = c * 256 + tid;
            int row = f >> 3;
            int kc = f & 7;
            split8h(A + (size_t)(m0 + row) * K + k0 + kc * 8,
                    &Ah[row][kc * 8], &Al[row][kc * 8]);
            *(short8*)&Wh[row][kc * 8] =
                *(const short8*)(whi + (size_t)(n0 + row) * K + k0 + kc * 8);
            *(short8*)&Wl[row][kc * 8] =
                *(const short8*)(wlo + (size_t)(n0 + row) * K + k0 + kc * 8);
        }
        __syncthreads();
#pragma unroll
        for (int ks = 0; ks < 2; ++ks) {
            short8 ah[4], al[4], bh[4], bl[4];
#pragma unroll
            for (int i = 0; i < 4; ++i) {
                ah[i] = *(const short8*)&Ah[msub + i * 16 + lrow][ks * 32 + quad * 8];
                al[i] = *(const short8*)&Al[msub + i * 16 + lrow][ks * 32 + quad * 8];
            }
#pragma unroll
            for (int j = 0; j < 4; ++j) {
                bh[j] = *(const short8*)&Wh[nsub + j * 16 + lrow][ks * 32 + quad * 8];
                bl[j] = *(const short8*)&Wl[nsub + j * 16 + lrow][ks * 32 + quad * 8];
            }
#pragma unroll
            for (int i = 0; i < 4; ++i)
#pragma unroll
                for (int j = 0; j < 4; ++j) {
                    acc[i][j] = __builtin_amdgcn_mfma_f32_16x16x32_bf16(ah[i], bh[j], acc[i][j], 0, 0, 0);
                    acc[i][j] = __builtin_amdgcn_mfma_f32_16x16x32_bf16(ah[i], bl[j], acc[i][j], 0, 0, 0);
                    acc[i][j] = __builtin_amdgcn_mfma_f32_16x16x32_bf16(al[i], bh[j], acc[i][j], 0, 0, 0);
                }
        }
    }

#pragma unroll
    for (int j = 0; j < 4; ++j) {
        int n = n0 + nsub + j * 16 + lrow;
        float bv = bias[n];
#pragma unroll
        for (int i = 0; i < 4; ++i)
#pragma unroll
            for (int r = 0; r < 4; ++r) {
                int m = m0 + msub + i * 16 + quad * 4 + r;
                C[(size_t)m * N + n] = (f16)(acc[i][j][r] + bv);
            }
    }
}

// ---------------------------------------------------------------------------
// Classifier: logits[BT,50] fp32 = out2[BT,1024] @ cls_w[50,1024]^T + cls_b.
// cls_w PRE-SPLIT planar bf16 hi/lo.
__global__ __launch_bounds__(256) void cls_gemm2(
    const f16* __restrict__ A, const bf16* __restrict__ wchi,
    const bf16* __restrict__ wclo, const float* __restrict__ bias,
    float* __restrict__ C) {
    __shared__ bf16 Ah[128][72], Al[128][72];
    __shared__ bf16 Wh[64][72], Wl[64][72];
    const int m0 = blockIdx.x * 128;
    const int tid = threadIdx.x;
    const int wave = tid >> 6;
    const int lane = tid & 63;
    const int lrow = lane & 15;
    const int quad = lane >> 4;
    const int msub = wave * 32;

    f32x4 acc[2][4];
#pragma unroll
    for (int i = 0; i < 2; ++i)
#pragma unroll
        for (int j = 0; j < 4; ++j) acc[i][j] = (f32x4){0.f, 0.f, 0.f, 0.f};

    for (int k0 = 0; k0 < 1024; k0 += 64) {
        __syncthreads();
#pragma unroll
        for (int c = 0; c < 4; ++c) {
            int f = c * 256 + tid;
            int row = f >> 3;
            int kc = f & 7;
            split8h(A + (size_t)(m0 + row) * 1024 + k0 + kc * 8,
                    &Ah[row][kc * 8], &Al[row][kc * 8]);
        }
#pragma unroll
        for (int c = 0; c < 2; ++c) {
            int f = c * 256 + tid;
            int row = f >> 3;
            int kc = f & 7;
            int wr = row < NTAGS ? row : NTAGS - 1;
            *(short8*)&Wh[row][kc * 8] =
                *(const short8*)(wchi + (size_t)wr * 1024 + k0 + kc * 8);
            *(short8*)&Wl[row][kc * 8] =
                *(const short8*)(wclo + (size_t)wr * 1024 + k0 + kc * 8);
        }
        __syncthreads();
#pragma unroll
        for (int ks = 0; ks < 2; ++ks) {
            short8 ah[2], al[2], bh[4], bl[4];
#pragma unroll
            for (int i = 0; i < 2; ++i) {
                ah[i] = *(const short8*)&Ah[msub + i * 16 + lrow][ks * 32 + quad * 8];
                al[i] = *(const short8*)&Al[msub + i * 16 + lrow][ks * 32 + quad * 8];
            }
#pragma unroll
            for (int j = 0; j < 4; ++j) {
                bh[j] = *(const short8*)&Wh[j * 16 + lrow][ks * 32 + quad * 8];
                bl[j] = *(const short8*)&Wl[j * 16 + lrow][ks * 32 + quad * 8];
            }
#pragma unroll
            for (int i = 0; i < 2; ++i)
#pragma unroll
                for (int j = 0; j < 4; ++j) {
                    acc[i][j] = __builtin_amdgcn_mfma_f32_16x16x32_bf16(ah[i], bh[j], acc[i][j], 0, 0, 0);
                    acc[i][j] = __builtin_amdgcn_mfma_f32_16x16x32_bf16(ah[i], bl[j], acc[i][j], 0, 0, 0);
                    acc[i][j] = __builtin_amdgcn_mfma_f32_16x16x32_bf16(al[i], bh[j], acc[i][j], 0, 0, 0);
                }
        }
    }

#pragma unroll
    for (int j = 0; j < 4; ++j) {
        int n = j * 16 + lrow;
        if (n < NTAGS) {
            float bv = bias[n];
#pragma unroll
            for (int i = 0; i < 2; ++i)
#pragma unroll
                for (int r = 0; r < 4; ++r) {
                    int m = m0 + msub + i * 16 + quad * 4 + r;
                    C[(size_t)m * NTAGS + n] = acc[i][j][r] + bv;
                }
        }
    }
}

// ---------------------------------------------------------------------------
// Persistent masked BiLSTM scan — EXACT R5 kernel (verified, 1554us/scan).
// Protocol: producers publish h with sc0sc1 dword stores, drain vmcnt(0),
// block barrier, tid0 stores the monotonic per-block flag (relaxed agent,
// 64B-spaced).  Consumer wave0 polls all 64 flags (one lane each, ballot),
// barrier releases the block, then all waves burst-load h with sc0sc1
// dwordx4 + counted vmcnt.  w-hi in registers, w-lo in lane-private LDS;
// wave-local gate phase (no post-MFMA block barrier, rule #18 fence).
__global__ __launch_bounds__(256, 1) void lstm_scan(
    const f16* __restrict__ xpre_f, const f16* __restrict__ xpre_b,
    const float* __restrict__ whh_f, const float* __restrict__ whh_b,
    const int* __restrict__ lengths,
    f16* __restrict__ out,      // [BT, 2H]
    bf16* __restrict__ hbuf,    // [dir][parity][hi/lo][64][512]
    int* __restrict__ bar, int base) {
    __shared__ bf16 w_lo2[32][64][8];  // [slot=nt*16+c][lane][8] : lane-private
    __shared__ float gat[64][33];      // [batch][gate*8+u], stride 33
    __shared__ int len_s[64];

    const int dir = blockIdx.x >> 6;
    const int sl = blockIdx.x & 63;
    const int tid = threadIdx.x;
    const int wave = tid >> 6;
    const int lane = tid & 63;
    const int lrow = lane & 15;
    const int quad = lane >> 4;
    // wave-local gate mapping: thread -> (batch gb in wave's 16, unit-pair)
    const int gb = wave * 16 + (lane >> 2);
    const int up = lane & 3;
    const int u0 = up * 2;

    const f16* xpre = dir ? xpre_b : xpre_f;
    const float* whh = dir ? whh_b : whh_f;
    bf16* hb = hbuf + (size_t)dir * 2 * 2 * BB * HH;
    int* flags = bar + dir * 1024;   // 64 single-producer flags, 64B apart
    int* myflag = flags + sl * 16;

    // ---- stage w_hh slice: hi -> regs BH[nt][c], lo -> lane-private LDS.
    short8 BH[2][16];
#pragma unroll
    for (int nt = 0; nt < 2; ++nt) {
        int R = nt * 16 + lrow;
        const float* wr = whh + (size_t)((R >> 3) * HH + sl * 8 + (R & 7)) * HH + quad * 8;
#pragma unroll
        for (int c = 0; c < 16; ++c) {
            float4 v0 = *(const float4*)(wr + c * 32);
            float4 v1 = *(const float4*)(wr + c * 32 + 4);
            float vv[8] = {v0.x, v0.y, v0.z, v0.w, v1.x, v1.y, v1.z, v1.w};
            short8 h8, l8;
#pragma unroll
            for (int j = 0; j < 8; ++j) {
                bf16 h = __float2bfloat16(vv[j]);
                h8[j] = (short)__bfloat16_as_ushort(h);
                l8[j] = f2bs(vv[j] - __bfloat162float(h));
            }
            BH[nt][c] = h8;
            *(short8*)&w_lo2[nt * 16 + c][lane][0] = l8;
        }
    }
    if (tid < 64) len_s[tid] = lengths[tid];
    __syncthreads();

    // persistent per-thread recurrent state (2 hidden units each)
    float hr0 = 0.f, hr1 = 0.f, cr0 = 0.f, cr1 = 0.f;

    // prefetch xpre for s = 0 (len >= 1 always)
    float pr[2][4];
    {
        int len = len_s[gb];
        int ta = dir ? (len - 1) : 0;
        const f16* xp = xpre + (size_t)(gb * TT + ta) * 2048 + sl * 8 + u0;
        half2v g0 = *(const half2v*)(xp);
        half2v g1 = *(const half2v*)(xp + 512);
        half2v g2 = *(const half2v*)(xp + 1024);
        half2v g3 = *(const half2v*)(xp + 1536);
        pr[0][0] = (float)g0[0]; pr[1][0] = (float)g0[1];
        pr[0][1] = (float)g1[0]; pr[1][1] = (float)g1[1];
        pr[0][2] = (float)g2[0]; pr[1][2] = (float)g2[1];
        pr[0][3] = (float)g3[0]; pr[1][3] = (float)g3[1];
    }

    for (int s = 0; s < TT; ++s) {
        if (s > 0) {
            const int target = base + s;

            // ---- wave0-only readiness poll; barrier releases the block
            if (wave == 0) {
                int* fp = &flags[lane * 16];
                int v = __hip_atomic_load(fp, __ATOMIC_RELAXED,
                                          __HIP_MEMORY_SCOPE_AGENT);
                while (__ballot(v >= target) != ~0ull) {
                    __builtin_amdgcn_s_sleep(1);
                    v = __hip_atomic_load(fp, __ATOMIC_RELAXED,
                                          __HIP_MEMORY_SCOPE_AGENT);
                }
            }
            __syncthreads();
            __asm__ volatile("" ::: "memory");

            // ---- burst-issue ALL h loads: 32 x dwordx4, sc0 sc1
            const int b = wave * 16 + lrow;
            const char* hpb = (const char*)hb +
                (size_t)(((s & 1) ^ 1) * 2) * BB * HH * sizeof(bf16);
            const char* hib = hpb + b * 1024 + quad * 16;
            const char* lob = hib + BB * HH * sizeof(bf16);  // +64KB

            short8 AH[16], AL[16];
#pragma unroll
            for (int c = 0; c < 16; ++c) {
                asm volatile("global_load_dwordx4 %0, %1, off offset:%2 sc0 sc1"
                             : "=v"(AH[c]) : "v"(hib), "n"(c * 64));
                asm volatile("global_load_dwordx4 %0, %1, off offset:%2 sc0 sc1"
                             : "=v"(AL[c]) : "v"(lob), "n"(c * 64));
            }

            // 4 accumulator chains: (nt, c&1)
            f32x4 ac[2][2];
            ac[0][0] = (f32x4){0.f, 0.f, 0.f, 0.f};
            ac[0][1] = (f32x4){0.f, 0.f, 0.f, 0.f};
            ac[1][0] = (f32x4){0.f, 0.f, 0.f, 0.f};
            ac[1][1] = (f32x4){0.f, 0.f, 0.f, 0.f};

            // first half ready at vmcnt(16) (in-order completion counting)
            asm volatile("s_waitcnt vmcnt(16)" ::: "memory");
            __builtin_amdgcn_sched_barrier(0);
#pragma unroll
            for (int c = 0; c < 8; ++c) {
#pragma unroll
                for (int nt = 0; nt < 2; ++nt) {
                    short8 bll = *(const short8*)&w_lo2[nt * 16 + c][lane][0];
                    ac[nt][c & 1] = __builtin_amdgcn_mfma_f32_16x16x32_bf16(AH[c], BH[nt][c], ac[nt][c & 1], 0, 0, 0);
                    ac[nt][c & 1] = __builtin_amdgcn_mfma_f32_16x16x32_bf16(AL[c], BH[nt][c], ac[nt][c & 1], 0, 0, 0);
                    ac[nt][c & 1] = __builtin_amdgcn_mfma_f32_16x16x32_bf16(AH[c], bll, ac[nt][c & 1], 0, 0, 0);
                }
            }
            asm volatile("s_waitcnt vmcnt(0)" ::: "memory");
            __builtin_amdgcn_sched_barrier(0);
#pragma unroll
            for (int c = 8; c < 16; ++c) {
#pragma unroll
                for (int nt = 0; nt < 2; ++nt) {
                    short8 bll = *(const short8*)&w_lo2[nt * 16 + c][lane][0];
                    ac[nt][c & 1] = __builtin_amdgcn_mfma_f32_16x16x32_bf16(AH[c], BH[nt][c], ac[nt][c & 1], 0, 0, 0);
                    ac[nt][c & 1] = __builtin_amdgcn_mfma_f32_16x16x32_bf16(AL[c], BH[nt][c], ac[nt][c & 1], 0, 0, 0);
                    ac[nt][c & 1] = __builtin_amdgcn_mfma_f32_16x16x32_bf16(AH[c], bll, ac[nt][c & 1], 0, 0, 0);
                }
            }
            // acc -> gat (wave-local rows only); rule #18 fence, no barrier.
#pragma unroll
            for (int nt = 0; nt < 2; ++nt)
#pragma unroll
                for (int r = 0; r < 4; ++r)
                    gat[wave * 16 + quad * 4 + r][nt * 16 + lrow] =
                        ac[nt][0][r] + ac[nt][1][r];
            asm volatile("s_waitcnt lgkmcnt(0)" ::: "memory");
            __builtin_amdgcn_sched_barrier(0);
        }

        // ---- gate phase: thread handles (gb, units u0,u0+1), wave-local ----
        const int len = len_s[gb];
        const bool act = (s < len);
        if (act) {
            float z0[4], z1[4];
#pragma unroll
            for (int g = 0; g < 4; ++g) { z0[g] = pr[0][g]; z1[g] = pr[1][g]; }
            if (s > 0) {
#pragma unroll
                for (int g = 0; g < 4; ++g) {
                    z0[g] += gat[gb][g * 8 + u0];
                    z1[g] += gat[gb][g * 8 + u0 + 1];
                }
            }
            float i0 = sigm(z0[0]), f0 = sigm(z0[1]);
            float g0 = tanh_f(z0[2]), o0 = sigm(z0[3]);
            float i1 = sigm(z1[0]), f1 = sigm(z1[1]);
            float g1 = tanh_f(z1[2]), o1 = sigm(z1[3]);
            cr0 = f0 * cr0 + i0 * g0;
            cr1 = f1 * cr1 + i1 * g1;
            hr0 = o0 * tanh_f(cr0);
            hr1 = o1 * tanh_f(cr1);
        }
        // publish hi/lo packed (always; carried h for masked rows): 4B sc0sc1
        {
            bf16 bh0 = __float2bfloat16(hr0);
            bf16 bh1 = __float2bfloat16(hr1);
            unsigned int hw = (unsigned int)__bfloat16_as_ushort(bh0) |
                              ((unsigned int)__bfloat16_as_ushort(bh1) << 16);
            float r0 = hr0 - __bfloat162float(bh0);
            float r1 = hr1 - __bfloat162float(bh1);
            unsigned int lw = (unsigned int)(unsigned short)f2bs(r0) |
                              ((unsigned int)(unsigned short)f2bs(r1) << 16);
            char* hcb = (char*)hb + (size_t)((s & 1) * 2) * BB * HH * sizeof(bf16);
            char* pa = hcb + gb * 1024 + (sl * 8 + u0) * 2;
            char* pb = pa + BB * HH * sizeof(bf16);
            asm volatile("global_store_dword %0, %1, off sc0 sc1"
                         :: "v"(pa), "v"(hw) : "memory");
            asm volatile("global_store_dword %0, %1, off sc0 sc1"
                         :: "v"(pb), "v"(lw) : "memory");
        }
        asm volatile("s_waitcnt vmcnt(0)" ::: "memory");  // drain h-stores
        __syncthreads();

        // signal: one fire-and-forget monotonic atomic STORE per block
        if (tid == 0)
            __hip_atomic_store(myflag, base + s + 1, __ATOMIC_RELAXED,
                               __HIP_MEMORY_SCOPE_AGENT);

        // off the inter-block critical path: prefetch next xpre, then out store
        if (s + 1 < TT) {
            if (s + 1 < len) {
                int ta = dir ? (len - 2 - s) : (s + 1);
                const f16* xp = xpre + (size_t)(gb * TT + ta) * 2048 + sl * 8 + u0;
                half2v g0 = *(const half2v*)(xp);
                half2v g1 = *(const half2v*)(xp + 512);
                half2v g2 = *(const half2v*)(xp + 1024);
                half2v g3 = *(const half2v*)(xp + 1536);
                pr[0][0] = (float)g0[0]; pr[1][0] = (float)g0[1];
                pr[0][1] = (float)g1[0]; pr[1][1] = (float)g1[1];
                pr[0][2] = (float)g2[0]; pr[1][2] = (float)g2[1];
                pr[0][3] = (float)g3[0]; pr[1][3] = (float)g3[1];
            }
        }
        if (act) {
            int ta = dir ? (len - 1 - s) : s;
            half2v ov; ov[0] = (f16)hr0; ov[1] = (f16)hr1;
            *(half2v*)(out + (size_t)(gb * TT + ta) * 1024 + dir * 512 + sl * 8 + u0) = ov;
        } else {
            half2v zv; zv[0] = (f16)0.f; zv[1] = (f16)0.f;
            *(half2v*)(out + (size_t)(gb * TT + s) * 1024 + dir * 512 + sl * 8 + u0) = zv;
        }
    }
}

// ---------------------------------------------------------------------------
extern "C" void kernel_launch(void* const* d_in, const int* in_sizes, int n_in,
                              void* d_out, int out_size, void* d_ws, size_t ws_size,
                              hipStream_t stream) {
    const int* x = (const int*)d_in[0];
    const int* lengths = (const int*)d_in[1];
    const float* emb = (const float*)d_in[2];
    const float* w_ih_f1 = (const float*)d_in[3];
    const float* w_hh_f1 = (const float*)d_in[4];
    const float* b_f1 = (const float*)d_in[5];
    const float* w_ih_b1 = (const float*)d_in[6];
    const float* w_hh_b1 = (const float*)d_in[7];
    const float* b_b1 = (const float*)d_in[8];
    const float* w_ih_f2 = (const float*)d_in[9];
    const float* w_hh_f2 = (const float*)d_in[10];
    const float* b_f2 = (const float*)d_in[11];
    const float* w_ih_b2 = (const float*)d_in[12];
    const float* w_hh_b2 = (const float*)d_in[13];
    const float* b_b2 = (const float*)d_in[14];
    const float* cls_w = (const float*)d_in[15];
    const float* cls_b = (const float*)d_in[16];
    float* logits = (float*)d_out;

    // workspace layout (bytes) — max touched offset 176 MB (proven envelope)
    // 0..8KB       bar (2 dirs x 64 flags, 64B apart)
    // 16KB..1.06MB hbuf
    // 2..10MB      e (f16, layer-1 A)  -> later ALIASED by w2 splits (e dead
    //              after the layer-1 GEMMs; stream order serializes)
    // 10..14MB     w1f/w1b splits (1MB each)
    // 14..14.5MB   cls_w splits
    // 16..80MB     xpre_f   80..144MB xpre_b   144..176MB out1/out2
    char* ws = (char*)d_ws;
    int* bar = (int*)ws;
    bf16* hbuf = (bf16*)(ws + 16384);
    f16* e = (f16*)(ws + 2097152);
    bf16* w2hi = (bf16*)(ws + 2097152);         // alias e: 2..6MB (4MB)
    bf16* w2lo = (bf16*)(ws + 6291456);         // 6..10MB
    bf16* w1f_hi = (bf16*)(ws + 10485760);      // 10..11MB
    bf16* w1f_lo = (bf16*)(ws + 11534336);      // 11..12MB
    bf16* w1b_hi = (bf16*)(ws + 12582912);      // 12..13MB
    bf16* w1b_lo = (bf16*)(ws + 13631488);      // 13..14MB
    bf16* wc_hi = (bf16*)(ws + 14680064);       // 14..14.1MB
    bf16* wc_lo = (bf16*)(ws + 14942208);       // 14.25..14.35MB
    f16* xpre_f = (f16*)(ws + 16777216);        // 16..80MB
    f16* xpre_b = (f16*)(ws + 83886080);        // 80..144MB
    f16* out1 = (f16*)(ws + 150994944);         // 144..176MB
    f16* out2 = out1;  // alias: out1 dead once layer-2 GEMMs complete

    bar_init<<<8, 256, 0, stream>>>(bar);
    split_w<<<256, 256, 0, stream>>>(w_ih_f1, w1f_hi, w1f_lo, 2048 * 256 / 8);
    split_w<<<256, 256, 0, stream>>>(w_ih_b1, w1b_hi, w1b_lo, 2048 * 256 / 8);
    split_w<<<25, 256, 0, stream>>>(cls_w, wc_hi, wc_lo, NTAGS * 1024 / 8);
    embed_gather<<<BT / 4, 256, 0, stream>>>(x, emb, e);

    dim3 g1(BT / 128, 2048 / 128);
    gemm_bt2<<<g1, 256, 0, stream>>>(e, w1f_hi, w1f_lo, b_f1, xpre_f, BT, 2048, EE);
    gemm_bt2<<<g1, 256, 0, stream>>>(e, w1b_hi, w1b_lo, b_b1, xpre_b, BT, 2048, EE);
    // e is dead now; stage layer-2 forward weight splits into its region
    split_w<<<1024, 256, 0, stream>>>(w_ih_f2, w2hi, w2lo, 2048 * 1024 / 8);
    lstm_scan<<<128, 256, 0, stream>>>(xpre_f, xpre_b, w_hh_f1, w_hh_b1,
                                       lengths, out1, hbuf, bar, 0);

    gemm_bt2<<<g1, 256, 0, stream>>>(out1, w2hi, w2lo, b_f2, xpre_f, BT, 2048, 2 * HH);
    // w2f splits consumed; overwrite with backward weights
    split_w<<<1024, 256, 0, stream>>>(w_ih_b2, w2hi, w2lo, 2048 * 1024 / 8);
    gemm_bt2<<<g1, 256, 0, stream>>>(out1, w2hi, w2lo, b_b2, xpre_b, BT, 2048, 2 * HH);
    lstm_scan<<<128, 256, 0, stream>>>(xpre_f, xpre_b, w_hh_f2, w_hh_b2,
                                       lengths, out2, hbuf, bar, TT);

    cls_gemm2<<<BT / 128, 256, 0, stream>>>(out2, wc_hi, wc_lo, cls_b, logits);
}

// Round 10
// 3158.663 us; speedup vs baseline: 1.3022x; 1.2952x over previous
//
#include <hip/hip_runtime.h>
#include <hip/hip_bf16.h>

// Problem constants
#define BB 64
#define TT 256
#define HH 512
#define EE 256
#define NTAGS 50
#define BT (BB * TT)  // 16384

typedef _Float16 f16;
typedef __attribute__((ext_vector_type(2))) _Float16 half2v;
typedef __attribute__((ext_vector_type(4))) _Float16 half4;
typedef __attribute__((ext_vector_type(8))) _Float16 half8;
typedef __attribute__((ext_vector_type(8))) short short8;
typedef __attribute__((ext_vector_type(4))) float f32x4;
typedef __hip_bfloat16 bf16;

__device__ __forceinline__ float sigm(float x) {
    return 1.f / (1.f + __expf(-x));
}
__device__ __forceinline__ float tanh_f(float x) {
    float ax = fabsf(x);
    float e = __expf(2.f * ax);
    float t = 1.f - 2.f / (e + 1.f);
    return x < 0.f ? -t : t;
}
__device__ __forceinline__ short f2bs(float f) {
    return (short)__bfloat16_as_ushort(__float2bfloat16(f));
}
// split 8 fp32 values (in regs) into bf16 hi + bf16 lo(residual)
__device__ __forceinline__ void split8v(const float* vv, bf16* hi, bf16* lo) {
    short8 h8, l8;
#pragma unroll
    for (int j = 0; j < 8; ++j) {
        bf16 h = __float2bfloat16(vv[j]);
        h8[j] = (short)__bfloat16_as_ushort(h);
        l8[j] = f2bs(vv[j] - __bfloat162float(h));
    }
    *(short8*)hi = h8;
    *(short8*)lo = l8;
}
__device__ __forceinline__ void split8(const float* p, bf16* hi, bf16* lo) {
    float4 v0 = *(const float4*)p;
    float4 v1 = *(const float4*)(p + 4);
    float vv[8] = {v0.x, v0.y, v0.z, v0.w, v1.x, v1.y, v1.z, v1.w};
    split8v(vv, hi, lo);
}
__device__ __forceinline__ void split8h(const f16* p, bf16* hi, bf16* lo) {
    half8 a = *(const half8*)p;
    float vv[8];
#pragma unroll
    for (int j = 0; j < 8; ++j) vv[j] = (float)a[j];
    split8v(vv, hi, lo);
}

// ---------------------------------------------------------------------------
// 2 dirs x 64 flags x 16-int (64B) spacing = 2048 ints = 8KB (R5-verified)
__global__ void bar_init(int* __restrict__ bar) {
    bar[blockIdx.x * 256 + threadIdx.x] = 0;
}

// ---------------------------------------------------------------------------
// embedding gather fp32 -> f16 storage
__global__ __launch_bounds__(256) void embed_gather(
    const int* __restrict__ x, const float* __restrict__ emb, f16* __restrict__ e) {
    int idx = blockIdx.x * 4 + (threadIdx.x >> 6);
    int lane = threadIdx.x & 63;
    int tok = x[idx];
    float4 v = *(const float4*)(emb + (size_t)tok * EE + lane * 4);
    half4 o;
    o[0] = (f16)v.x; o[1] = (f16)v.y; o[2] = (f16)v.z; o[3] = (f16)v.w;
    *(half4*)(e + (size_t)idx * EE + lane * 4) = o;
}

// ---------------------------------------------------------------------------
// C[M,N] = A[M,K] @ W[N,K]^T + bias[N].  A: f16 storage, W/bias fp32.
// Both split to bf16 hi+lo in LDS; 3 MFMA products -> ~fp32 accuracy. f16 out.
// (R5-exact: R9 showed the GEMM is latency-bound, not staging-VALU-bound —
// W pre-split was null and its serial split_w launches cost ~80us. Reverted.)
__global__ __launch_bounds__(256) void gemm_bt(
    const f16* __restrict__ A, const float* __restrict__ W,
    const float* __restrict__ bias, f16* __restrict__ C,
    int M, int N, int K) {
    __shared__ bf16 Ah[128][72], Al[128][72];
    __shared__ bf16 Wh[128][72], Wl[128][72];
    const int m0 = blockIdx.x * 128;
    const int n0 = blockIdx.y * 128;
    const int tid = threadIdx.x;
    const int wave = tid >> 6;
    const int lane = tid & 63;
    const int lrow = lane & 15;
    const int quad = lane >> 4;
    const int msub = (wave >> 1) * 64;
    const int nsub = (wave & 1) * 64;

    f32x4 acc[4][4];
#pragma unroll
    for (int i = 0; i < 4; ++i)
#pragma unroll
        for (int j = 0; j < 4; ++j) acc[i][j] = (f32x4){0.f, 0.f, 0.f, 0.f};

    for (int k0 = 0; k0 < K; k0 += 64) {
        __syncthreads();
#pragma unroll
        for (int c = 0; c < 4; ++c) {
            int f = c * 256 + tid;
            int row = f >> 3;
            int kc = f & 7;
            split8h(A + (size_t)(m0 + row) * K + k0 + kc * 8,
                    &Ah[row][kc * 8], &Al[row][kc * 8]);
            split8(W + (size_t)(n0 + row) * K + k0 + kc * 8,
                   &Wh[row][kc * 8], &Wl[row][kc * 8]);
        }
        __syncthreads();
#pragma unroll
        for (int ks = 0; ks < 2; ++ks) {
            short8 ah[4], al[4], bh[4], bl[4];
#pragma unroll
            for (int i = 0; i < 4; ++i) {
                ah[i] = *(const short8*)&Ah[msub + i * 16 + lrow][ks * 32 + quad * 8];
                al[i] = *(const short8*)&Al[msub + i * 16 + lrow][ks * 32 + quad * 8];
            }
#pragma unroll
            for (int j = 0; j < 4; ++j) {
                bh[j] = *(const short8*)&Wh[nsub + j * 16 + lrow][ks * 32 + quad * 8];
                bl[j] = *(const short8*)&Wl[nsub + j * 16 + lrow][ks * 32 + quad * 8];
            }
#pragma unroll
            for (int i = 0; i < 4; ++i)
#pragma unroll
                for (int j = 0; j < 4; ++j) {
                    acc[i][j] = __builtin_amdgcn_mfma_f32_16x16x32_bf16(ah[i], bh[j], acc[i][j], 0, 0, 0);
                    acc[i][j] = __builtin_amdgcn_mfma_f32_16x16x32_bf16(ah[i], bl[j], acc[i][j], 0, 0, 0);
                    acc[i][j] = __builtin_amdgcn_mfma_f32_16x16x32_bf16(al[i], bh[j], acc[i][j], 0, 0, 0);
                }
        }
    }

#pragma unroll
    for (int j = 0; j < 4; ++j) {
        int n = n0 + nsub + j * 16 + lrow;
        float bv = bias[n];
#pragma unroll
        for (int i = 0; i < 4; ++i)
#pragma unroll
            for (int r = 0; r < 4; ++r) {
                int m = m0 + msub + i * 16 + quad * 4 + r;
                C[(size_t)m * N + n] = (f16)(acc[i][j][r] + bv);
            }
    }
}

// ---------------------------------------------------------------------------
// Classifier: logits[BT,50] fp32 = out2[BT,1024] @ cls_w[50,1024]^T + cls_b.
__global__ __launch_bounds__(256) void cls_gemm(
    const f16* __restrict__ A, const float* __restrict__ W,
    const float* __restrict__ bias, float* __restrict__ C) {
    __shared__ bf16 Ah[128][72], Al[128][72];
    __shared__ bf16 Wh[64][72], Wl[64][72];
    const int m0 = blockIdx.x * 128;
    const int tid = threadIdx.x;
    const int wave = tid >> 6;
    const int lane = tid & 63;
    const int lrow = lane & 15;
    const int quad = lane >> 4;
    const int msub = wave * 32;

    f32x4 acc[2][4];
#pragma unroll
    for (int i = 0; i < 2; ++i)
#pragma unroll
        for (int j = 0; j < 4; ++j) acc[i][j] = (f32x4){0.f, 0.f, 0.f, 0.f};

    for (int k0 = 0; k0 < 1024; k0 += 64) {
        __syncthreads();
#pragma unroll
        for (int c = 0; c < 4; ++c) {
            int f = c * 256 + tid;
            int row = f >> 3;
            int kc = f & 7;
            split8h(A + (size_t)(m0 + row) * 1024 + k0 + kc * 8,
                    &Ah[row][kc * 8], &Al[row][kc * 8]);
        }
#pragma unroll
        for (int c = 0; c < 2; ++c) {
            int f = c * 256 + tid;
            int row = f >> 3;
            int kc = f & 7;
            int wr = row < NTAGS ? row : NTAGS - 1;
            split8(W + (size_t)wr * 1024 + k0 + kc * 8,
                   &Wh[row][kc * 8], &Wl[row][kc * 8]);
        }
        __syncthreads();
#pragma unroll
        for (int ks = 0; ks < 2; ++ks) {
            short8 ah[2], al[2], bh[4], bl[4];
#pragma unroll
            for (int i = 0; i < 2; ++i) {
                ah[i] = *(const short8*)&Ah[msub + i * 16 + lrow][ks * 32 + quad * 8];
                al[i] = *(const short8*)&Al[msub + i * 16 + lrow][ks * 32 + quad * 8];
            }
#pragma unroll
            for (int j = 0; j < 4; ++j) {
                bh[j] = *(const short8*)&Wh[j * 16 + lrow][ks * 32 + quad * 8];
                bl[j] = *(const short8*)&Wl[j * 16 + lrow][ks * 32 + quad * 8];
            }
#pragma unroll
            for (int i = 0; i < 2; ++i)
#pragma unroll
                for (int j = 0; j < 4; ++j) {
                    acc[i][j] = __builtin_amdgcn_mfma_f32_16x16x32_bf16(ah[i], bh[j], acc[i][j], 0, 0, 0);
                    acc[i][j] = __builtin_amdgcn_mfma_f32_16x16x32_bf16(ah[i], bl[j], acc[i][j], 0, 0, 0);
                    acc[i][j] = __builtin_amdgcn_mfma_f32_16x16x32_bf16(al[i], bh[j], acc[i][j], 0, 0, 0);
                }
        }
    }

#pragma unroll
    for (int j = 0; j < 4; ++j) {
        int n = j * 16 + lrow;
        if (n < NTAGS) {
            float bv = bias[n];
#pragma unroll
            for (int i = 0; i < 2; ++i)
#pragma unroll
                for (int r = 0; r < 4; ++r) {
                    int m = m0 + msub + i * 16 + quad * 4 + r;
                    C[(size_t)m * NTAGS + n] = acc[i][j][r] + bv;
                }
        }
    }
}

// ---------------------------------------------------------------------------
// Persistent masked BiLSTM scan — R5 protocol (verified) with h exchanged
// HI-ONLY.  The h bf16-residual's contribution to the gate pre-activation
// (AL.BH product) is ~1e-4 RMS — dropped.  W keeps hi+lo (LDS-resident,
// free), so 2 MFMA products remain: AH.BH + AH.BL.  Payoff: producer 1
// store (was 2), shorter drain; consumer 16 loads (was 32), 8 MB/step
// broadcast (was 16); MFMA 64/step (was 96).
//
// Protocol (R5-verified, unchanged): producers publish h with sc0sc1 dword
// stores, drain vmcnt(0), block barrier, tid0 stores the monotonic
// per-block flag (relaxed agent, 64B-spaced).  Consumer wave0 polls all 64
// flags (one lane each, ballot), barrier releases the block, then all
// waves burst-load h with sc0sc1 dwordx4 + counted vmcnt.
__global__ __launch_bounds__(256, 1) void lstm_scan(
    const f16* __restrict__ xpre_f, const f16* __restrict__ xpre_b,
    const float* __restrict__ whh_f, const float* __restrict__ whh_b,
    const int* __restrict__ lengths,
    f16* __restrict__ out,      // [BT, 2H]
    bf16* __restrict__ hbuf,    // [dir][parity][hi(+unused lo)][64][512]
    int* __restrict__ bar, int base) {
    __shared__ bf16 w_lo2[32][64][8];  // [slot=nt*16+c][lane][8] : lane-private
    __shared__ float gat[64][33];      // [batch][gate*8+u], stride 33
    __shared__ int len_s[64];

    const int dir = blockIdx.x >> 6;
    const int sl = blockIdx.x & 63;
    const int tid = threadIdx.x;
    const int wave = tid >> 6;
    const int lane = tid & 63;
    const int lrow = lane & 15;
    const int quad = lane >> 4;
    // wave-local gate mapping: thread -> (batch gb in wave's 16, unit-pair)
    const int gb = wave * 16 + (lane >> 2);
    const int up = lane & 3;
    const int u0 = up * 2;

    const f16* xpre = dir ? xpre_b : xpre_f;
    const float* whh = dir ? whh_b : whh_f;
    bf16* hb = hbuf + (size_t)dir * 2 * 2 * BB * HH;
    int* flags = bar + dir * 1024;   // 64 single-producer flags, 64B apart
    int* myflag = flags + sl * 16;

    // ---- stage w_hh slice: hi -> regs BH[nt][c], lo -> lane-private LDS.
    short8 BH[2][16];
#pragma unroll
    for (int nt = 0; nt < 2; ++nt) {
        int R = nt * 16 + lrow;
        const float* wr = whh + (size_t)((R >> 3) * HH + sl * 8 + (R & 7)) * HH + quad * 8;
#pragma unroll
        for (int c = 0; c < 16; ++c) {
            float4 v0 = *(const float4*)(wr + c * 32);
            float4 v1 = *(const float4*)(wr + c * 32 + 4);
            float vv[8] = {v0.x, v0.y, v0.z, v0.w, v1.x, v1.y, v1.z, v1.w};
            short8 h8, l8;
#pragma unroll
            for (int j = 0; j < 8; ++j) {
                bf16 h = __float2bfloat16(vv[j]);
                h8[j] = (short)__bfloat16_as_ushort(h);
                l8[j] = f2bs(vv[j] - __bfloat162float(h));
            }
            BH[nt][c] = h8;
            *(short8*)&w_lo2[nt * 16 + c][lane][0] = l8;
        }
    }
    if (tid < 64) len_s[tid] = lengths[tid];
    __syncthreads();

    // persistent per-thread recurrent state (2 hidden units each)
    float hr0 = 0.f, hr1 = 0.f, cr0 = 0.f, cr1 = 0.f;

    // prefetch xpre for s = 0 (len >= 1 always)
    float pr[2][4];
    {
        int len = len_s[gb];
        int ta = dir ? (len - 1) : 0;
        const f16* xp = xpre + (size_t)(gb * TT + ta) * 2048 + sl * 8 + u0;
        half2v g0 = *(const half2v*)(xp);
        half2v g1 = *(const half2v*)(xp + 512);
        half2v g2 = *(const half2v*)(xp + 1024);
        half2v g3 = *(const half2v*)(xp + 1536);
        pr[0][0] = (float)g0[0]; pr[1][0] = (float)g0[1];
        pr[0][1] = (float)g1[0]; pr[1][1] = (float)g1[1];
        pr[0][2] = (float)g2[0]; pr[1][2] = (float)g2[1];
        pr[0][3] = (float)g3[0]; pr[1][3] = (float)g3[1];
    }

    for (int s = 0; s < TT; ++s) {
        if (s > 0) {
            const int target = base + s;

            // ---- wave0-only readiness poll; barrier releases the block
            if (wave == 0) {
                int* fp = &flags[lane * 16];
                int v = __hip_atomic_load(fp, __ATOMIC_RELAXED,
                                          __HIP_MEMORY_SCOPE_AGENT);
                while (__ballot(v >= target) != ~0ull) {
                    __builtin_amdgcn_s_sleep(1);
                    v = __hip_atomic_load(fp, __ATOMIC_RELAXED,
                                          __HIP_MEMORY_SCOPE_AGENT);
                }
            }
            __syncthreads();
            __asm__ volatile("" ::: "memory");

            // ---- burst-issue h-hi loads: 16 x dwordx4, sc0 sc1
            const int b = wave * 16 + lrow;
            const char* hpb = (const char*)hb +
                (size_t)(((s & 1) ^ 1) * 2) * BB * HH * sizeof(bf16);
            const char* hib = hpb + b * 1024 + quad * 16;

            short8 AH[16];
#pragma unroll
            for (int c = 0; c < 16; ++c) {
                asm volatile("global_load_dwordx4 %0, %1, off offset:%2 sc0 sc1"
                             : "=v"(AH[c]) : "v"(hib), "n"(c * 64));
            }

            // 4 accumulator chains: (nt, c&1)
            f32x4 ac[2][2];
            ac[0][0] = (f32x4){0.f, 0.f, 0.f, 0.f};
            ac[0][1] = (f32x4){0.f, 0.f, 0.f, 0.f};
            ac[1][0] = (f32x4){0.f, 0.f, 0.f, 0.f};
            ac[1][1] = (f32x4){0.f, 0.f, 0.f, 0.f};

            // first half ready at vmcnt(8) (in-order completion counting)
            asm volatile("s_waitcnt vmcnt(8)" ::: "memory");
            __builtin_amdgcn_sched_barrier(0);
#pragma unroll
            for (int c = 0; c < 8; ++c) {
#pragma unroll
                for (int nt = 0; nt < 2; ++nt) {
                    short8 bll = *(const short8*)&w_lo2[nt * 16 + c][lane][0];
                    ac[nt][c & 1] = __builtin_amdgcn_mfma_f32_16x16x32_bf16(AH[c], BH[nt][c], ac[nt][c & 1], 0, 0, 0);
                    ac[nt][c & 1] = __builtin_amdgcn_mfma_f32_16x16x32_bf16(AH[c], bll, ac[nt][c & 1], 0, 0, 0);
                }
            }
            asm volatile("s_waitcnt vmcnt(0)" ::: "memory");
            __builtin_amdgcn_sched_barrier(0);
#pragma unroll
            for (int c = 8; c < 16; ++c) {
#pragma unroll
                for (int nt = 0; nt < 2; ++nt) {
                    short8 bll = *(const short8*)&w_lo2[nt * 16 + c][lane][0];
                    ac[nt][c & 1] = __builtin_amdgcn_mfma_f32_16x16x32_bf16(AH[c], BH[nt][c], ac[nt][c & 1], 0, 0, 0);
                    ac[nt][c & 1] = __builtin_amdgcn_mfma_f32_16x16x32_bf16(AH[c], bll, ac[nt][c & 1], 0, 0, 0);
                }
            }
            // acc -> gat (wave-local rows only); rule #18 fence, no barrier.
#pragma unroll
            for (int nt = 0; nt < 2; ++nt)
#pragma unroll
                for (int r = 0; r < 4; ++r)
                    gat[wave * 16 + quad * 4 + r][nt * 16 + lrow] =
                        ac[nt][0][r] + ac[nt][1][r];
            asm volatile("s_waitcnt lgkmcnt(0)" ::: "memory");
            __builtin_amdgcn_sched_barrier(0);
        }

        // ---- gate phase: thread handles (gb, units u0,u0+1), wave-local ----
        const int len = len_s[gb];
        const bool act = (s < len);
        if (act) {
            float z0[4], z1[4];
#pragma unroll
            for (int g = 0; g < 4; ++g) { z0[g] = pr[0][g]; z1[g] = pr[1][g]; }
            if (s > 0) {
#pragma unroll
                for (int g = 0; g < 4; ++g) {
                    z0[g] += gat[gb][g * 8 + u0];
                    z1[g] += gat[gb][g * 8 + u0 + 1];
                }
            }
            float i0 = sigm(z0[0]), f0 = sigm(z0[1]);
            float g0 = tanh_f(z0[2]), o0 = sigm(z0[3]);
            float i1 = sigm(z1[0]), f1 = sigm(z1[1]);
            float g1 = tanh_f(z1[2]), o1 = sigm(z1[3]);
            cr0 = f0 * cr0 + i0 * g0;
            cr1 = f1 * cr1 + i1 * g1;
            hr0 = o0 * tanh_f(cr0);
            hr1 = o1 * tanh_f(cr1);
        }
        // publish h-hi packed (always; carried h for masked rows): 4B sc0sc1
        {
            bf16 bh0 = __float2bfloat16(hr0);
            bf16 bh1 = __float2bfloat16(hr1);
            unsigned int hw = (unsigned int)__bfloat16_as_ushort(bh0) |
                              ((unsigned int)__bfloat16_as_ushort(bh1) << 16);
            char* hcb = (char*)hb + (size_t)((s & 1) * 2) * BB * HH * sizeof(bf16);
            char* pa = hcb + gb * 1024 + (sl * 8 + u0) * 2;
            asm volatile("global_store_dword %0, %1, off sc0 sc1"
                         :: "v"(pa), "v"(hw) : "memory");
        }
        asm volatile("s_waitcnt vmcnt(0)" ::: "memory");  // drain h-stores
        __syncthreads();

        // signal: one fire-and-forget monotonic atomic STORE per block
        if (tid == 0)
            __hip_atomic_store(myflag, base + s + 1, __ATOMIC_RELAXED,
                               __HIP_MEMORY_SCOPE_AGENT);

        // off the inter-block critical path: prefetch next xpre, then out store
        if (s + 1 < TT) {
            if (s + 1 < len) {
                int ta = dir ? (len - 2 - s) : (s + 1);
                const f16* xp = xpre + (size_t)(gb * TT + ta) * 2048 + sl * 8 + u0;
                half2v g0 = *(const half2v*)(xp);
                half2v g1 = *(const half2v*)(xp + 512);
                half2v g2 = *(const half2v*)(xp + 1024);
                half2v g3 = *(const half2v*)(xp + 1536);
                pr[0][0] = (float)g0[0]; pr[1][0] = (float)g0[1];
                pr[0][1] = (float)g1[0]; pr[1][1] = (float)g1[1];
                pr[0][2] = (float)g2[0]; pr[1][2] = (float)g2[1];
                pr[0][3] = (float)g3[0]; pr[1][3] = (float)g3[1];
            }
        }
        if (act) {
            int ta = dir ? (len - 1 - s) : s;
            half2v ov; ov[0] = (f16)hr0; ov[1] = (f16)hr1;
            *(half2v*)(out + (size_t)(gb * TT + ta) * 1024 + dir * 512 + sl * 8 + u0) = ov;
        } else {
            half2v zv; zv[0] = (f16)0.f; zv[1] = (f16)0.f;
            *(half2v*)(out + (size_t)(gb * TT + s) * 1024 + dir * 512 + sl * 8 + u0) = zv;
        }
    }
}

// ---------------------------------------------------------------------------
extern "C" void kernel_launch(void* const* d_in, const int* in_sizes, int n_in,
                              void* d_out, int out_size, void* d_ws, size_t ws_size,
                              hipStream_t stream) {
    const int* x = (const int*)d_in[0];
    const int* lengths = (const int*)d_in[1];
    const float* emb = (const float*)d_in[2];
    const float* w_ih_f1 = (const float*)d_in[3];
    const float* w_hh_f1 = (const float*)d_in[4];
    const float* b_f1 = (const float*)d_in[5];
    const float* w_ih_b1 = (const float*)d_in[6];
    const float* w_hh_b1 = (const float*)d_in[7];
    const float* b_b1 = (const float*)d_in[8];
    const float* w_ih_f2 = (const float*)d_in[9];
    const float* w_hh_f2 = (const float*)d_in[10];
    const float* b_f2 = (const float*)d_in[11];
    const float* w_ih_b2 = (const float*)d_in[12];
    const float* w_hh_b2 = (const float*)d_in[13];
    const float* b_b2 = (const float*)d_in[14];
    const float* cls_w = (const float*)d_in[15];
    const float* cls_b = (const float*)d_in[16];
    float* logits = (float*)d_out;

    // workspace layout (bytes) — max touched offset ~176 MB (proven envelope)
    char* ws = (char*)d_ws;
    int* bar = (int*)ws;                        // 0 .. 8 KB (2x64 flags, 64B apart)
    bf16* hbuf = (bf16*)(ws + 16384);           // 16 KB .. ~1.06 MB
    f16* e = (f16*)(ws + 2097152);              // 2 MB .. 10 MB
    f16* xpre_f = (f16*)(ws + 16777216);        // 16 MB .. 80 MB
    f16* xpre_b = (f16*)(ws + 83886080);        // 80 MB .. 144 MB
    f16* out1 = (f16*)(ws + 150994944);         // 144 MB .. 176 MB
    f16* out2 = out1;  // alias: out1 dead once layer-2 GEMMs complete

    bar_init<<<8, 256, 0, stream>>>(bar);
    embed_gather<<<BT / 4, 256, 0, stream>>>(x, emb, e);

    dim3 g1(BT / 128, 2048 / 128);
    gemm_bt<<<g1, 256, 0, stream>>>(e, w_ih_f1, b_f1, xpre_f, BT, 2048, EE);
    gemm_bt<<<g1, 256, 0, stream>>>(e, w_ih_b1, b_b1, xpre_b, BT, 2048, EE);
    lstm_scan<<<128, 256, 0, stream>>>(xpre_f, xpre_b, w_hh_f1, w_hh_b1,
                                       lengths, out1, hbuf, bar, 0);

    gemm_bt<<<g1, 256, 0, stream>>>(out1, w_ih_f2, b_f2, xpre_f, BT, 2048, 2 * HH);
    gemm_bt<<<g1, 256, 0, stream>>>(out1, w_ih_b2, b_b2, xpre_b, BT, 2048, 2 * HH);
    lstm_scan<<<128, 256, 0, stream>>>(xpre_f, xpre_b, w_hh_f2, w_hh_b2,
                                       lengths, out2, hbuf, bar, TT);

    cls_gemm<<<BT / 128, 256, 0, stream>>>(out2, cls_w, cls_b, logits);
}

// Round 11
// 2865.045 us; speedup vs baseline: 1.4356x; 1.1025x over previous
//
#include <hip/hip_runtime.h>
#include <hip/hip_bf16.h>

// Problem constants
#define BB 64
#define TT 256
#define HH 512
#define EE 256
#define NTAGS 50
#define BT (BB * TT)  // 16384

typedef _Float16 f16;
typedef __attribute__((ext_vector_type(2))) _Float16 half2v;
typedef __attribute__((ext_vector_type(4))) _Float16 half4;
typedef __attribute__((ext_vector_type(8))) _Float16 half8;
typedef __attribute__((ext_vector_type(8))) short short8;
typedef __attribute__((ext_vector_type(4))) float f32x4;
typedef __hip_bfloat16 bf16;

__device__ __forceinline__ float sigm(float x) {
    return 1.f / (1.f + __expf(-x));
}
__device__ __forceinline__ float tanh_f(float x) {
    float ax = fabsf(x);
    float e = __expf(2.f * ax);
    float t = 1.f - 2.f / (e + 1.f);
    return x < 0.f ? -t : t;
}
__device__ __forceinline__ short f2bs(float f) {
    return (short)__bfloat16_as_ushort(__float2bfloat16(f));
}
// split 8 fp32 values (in regs) into bf16 hi + bf16 lo(residual)
__device__ __forceinline__ void split8v(const float* vv, bf16* hi, bf16* lo) {
    short8 h8, l8;
#pragma unroll
    for (int j = 0; j < 8; ++j) {
        bf16 h = __float2bfloat16(vv[j]);
        h8[j] = (short)__bfloat16_as_ushort(h);
        l8[j] = f2bs(vv[j] - __bfloat162float(h));
    }
    *(short8*)hi = h8;
    *(short8*)lo = l8;
}
__device__ __forceinline__ void split8(const float* p, bf16* hi, bf16* lo) {
    float4 v0 = *(const float4*)p;
    float4 v1 = *(const float4*)(p + 4);
    float vv[8] = {v0.x, v0.y, v0.z, v0.w, v1.x, v1.y, v1.z, v1.w};
    split8v(vv, hi, lo);
}
__device__ __forceinline__ void split8h(const f16* p, bf16* hi, bf16* lo) {
    half8 a = *(const half8*)p;
    float vv[8];
#pragma unroll
    for (int j = 0; j < 8; ++j) vv[j] = (float)a[j];
    split8v(vv, hi, lo);
}
// f16 -> bf16 hi only (no residual): for A-hi-only layer-2 staging
__device__ __forceinline__ void cvt8h(const f16* p, bf16* hi) {
    half8 a = *(const half8*)p;
    short8 h8;
#pragma unroll
    for (int j = 0; j < 8; ++j)
        h8[j] = (short)__bfloat16_as_ushort(__float2bfloat16((float)a[j]));
    *(short8*)hi = h8;
}

// ---------------------------------------------------------------------------
// 2 dirs x 64 flags x 16-int (64B) spacing = 2048 ints = 8KB (R5-verified)
__global__ void bar_init(int* __restrict__ bar) {
    bar[blockIdx.x * 256 + threadIdx.x] = 0;
}

// ---------------------------------------------------------------------------
// FUSED embed + layer-1 GEMM:
// C[BT,2048] = emb[x][BT,256] @ W[2048,256]^T + bias.  A gathered straight
// from fp32 emb rows (exact hi/lo split — MORE precise than the old f16 e
// round-trip) ; 3 MFMA products.  Removes the embed kernel + 16MB e buffer.
__global__ __launch_bounds__(256) void gemm_emb(
    const int* __restrict__ x, const float* __restrict__ emb,
    const float* __restrict__ W, const float* __restrict__ bias,
    f16* __restrict__ C) {
    __shared__ bf16 Ah[128][72], Al[128][72];
    __shared__ bf16 Wh[128][72], Wl[128][72];
    const int m0 = blockIdx.x * 128;
    const int n0 = blockIdx.y * 128;
    const int tid = threadIdx.x;
    const int wave = tid >> 6;
    const int lane = tid & 63;
    const int lrow = lane & 15;
    const int quad = lane >> 4;
    const int msub = (wave >> 1) * 64;
    const int nsub = (wave & 1) * 64;

    int tok[4];
#pragma unroll
    for (int c = 0; c < 4; ++c)
        tok[c] = x[m0 + ((c * 256 + tid) >> 3)];

    f32x4 acc[4][4];
#pragma unroll
    for (int i = 0; i < 4; ++i)
#pragma unroll
        for (int j = 0; j < 4; ++j) acc[i][j] = (f32x4){0.f, 0.f, 0.f, 0.f};

    for (int k0 = 0; k0 < EE; k0 += 64) {
        __syncthreads();
#pragma unroll
        for (int c = 0; c < 4; ++c) {
            int f = c * 256 + tid;
            int row = f >> 3;
            int kc = f & 7;
            split8(emb + (size_t)tok[c] * EE + k0 + kc * 8,
                   &Ah[row][kc * 8], &Al[row][kc * 8]);
            split8(W + (size_t)(n0 + row) * EE + k0 + kc * 8,
                   &Wh[row][kc * 8], &Wl[row][kc * 8]);
        }
        __syncthreads();
#pragma unroll
        for (int ks = 0; ks < 2; ++ks) {
            short8 ah[4], al[4], bh[4], bl[4];
#pragma unroll
            for (int i = 0; i < 4; ++i) {
                ah[i] = *(const short8*)&Ah[msub + i * 16 + lrow][ks * 32 + quad * 8];
                al[i] = *(const short8*)&Al[msub + i * 16 + lrow][ks * 32 + quad * 8];
            }
#pragma unroll
            for (int j = 0; j < 4; ++j) {
                bh[j] = *(const short8*)&Wh[nsub + j * 16 + lrow][ks * 32 + quad * 8];
                bl[j] = *(const short8*)&Wl[nsub + j * 16 + lrow][ks * 32 + quad * 8];
            }
#pragma unroll
            for (int i = 0; i < 4; ++i)
#pragma unroll
                for (int j = 0; j < 4; ++j) {
                    acc[i][j] = __builtin_amdgcn_mfma_f32_16x16x32_bf16(ah[i], bh[j], acc[i][j], 0, 0, 0);
                    acc[i][j] = __builtin_amdgcn_mfma_f32_16x16x32_bf16(ah[i], bl[j], acc[i][j], 0, 0, 0);
                    acc[i][j] = __builtin_amdgcn_mfma_f32_16x16x32_bf16(al[i], bh[j], acc[i][j], 0, 0, 0);
                }
        }
    }

#pragma unroll
    for (int j = 0; j < 4; ++j) {
        int n = n0 + nsub + j * 16 + lrow;
        float bv = bias[n];
#pragma unroll
        for (int i = 0; i < 4; ++i)
#pragma unroll
            for (int r = 0; r < 4; ++r) {
                int m = m0 + msub + i * 16 + quad * 4 + r;
                C[(size_t)m * 2048 + n] = (f16)(acc[i][j][r] + bv);
            }
    }
}

// ---------------------------------------------------------------------------
// Layer-2 GEMM: C[BT,2048] = A[BT,1024] @ W[2048,1024]^T + bias.
// A bf16-HI-ONLY (residual dropped: ~1.6e-4 z-error), W hi+lo kept ->
// 2 MFMA products (was 3), Ah-only LDS (54KB, was 72KB).
__global__ __launch_bounds__(256) void gemm_l2(
    const f16* __restrict__ A, const float* __restrict__ W,
    const float* __restrict__ bias, f16* __restrict__ C) {
    __shared__ bf16 Ah[128][72];
    __shared__ bf16 Wh[128][72], Wl[128][72];
    const int m0 = blockIdx.x * 128;
    const int n0 = blockIdx.y * 128;
    const int tid = threadIdx.x;
    const int wave = tid >> 6;
    const int lane = tid & 63;
    const int lrow = lane & 15;
    const int quad = lane >> 4;
    const int msub = (wave >> 1) * 64;
    const int nsub = (wave & 1) * 64;

    f32x4 acc[4][4];
#pragma unroll
    for (int i = 0; i < 4; ++i)
#pragma unroll
        for (int j = 0; j < 4; ++j) acc[i][j] = (f32x4){0.f, 0.f, 0.f, 0.f};

    for (int k0 = 0; k0 < 1024; k0 += 64) {
        __syncthreads();
#pragma unroll
        for (int c = 0; c < 4; ++c) {
            int f = c * 256 + tid;
            int row = f >> 3;
            int kc = f & 7;
            cvt8h(A + (size_t)(m0 + row) * 1024 + k0 + kc * 8, &Ah[row][kc * 8]);
            split8(W + (size_t)(n0 + row) * 1024 + k0 + kc * 8,
                   &Wh[row][kc * 8], &Wl[row][kc * 8]);
        }
        __syncthreads();
#pragma unroll
        for (int ks = 0; ks < 2; ++ks) {
            short8 ah[4], bh[4], bl[4];
#pragma unroll
            for (int i = 0; i < 4; ++i)
                ah[i] = *(const short8*)&Ah[msub + i * 16 + lrow][ks * 32 + quad * 8];
#pragma unroll
            for (int j = 0; j < 4; ++j) {
                bh[j] = *(const short8*)&Wh[nsub + j * 16 + lrow][ks * 32 + quad * 8];
                bl[j] = *(const short8*)&Wl[nsub + j * 16 + lrow][ks * 32 + quad * 8];
            }
#pragma unroll
            for (int i = 0; i < 4; ++i)
#pragma unroll
                for (int j = 0; j < 4; ++j) {
                    acc[i][j] = __builtin_amdgcn_mfma_f32_16x16x32_bf16(ah[i], bh[j], acc[i][j], 0, 0, 0);
                    acc[i][j] = __builtin_amdgcn_mfma_f32_16x16x32_bf16(ah[i], bl[j], acc[i][j], 0, 0, 0);
                }
        }
    }

#pragma unroll
    for (int j = 0; j < 4; ++j) {
        int n = n0 + nsub + j * 16 + lrow;
        float bv = bias[n];
#pragma unroll
        for (int i = 0; i < 4; ++i)
#pragma unroll
            for (int r = 0; r < 4; ++r) {
                int m = m0 + msub + i * 16 + quad * 4 + r;
                C[(size_t)m * 2048 + n] = (f16)(acc[i][j][r] + bv);
            }
    }
}

// ---------------------------------------------------------------------------
// Classifier: logits[BT,50] fp32 = out2[BT,1024] @ cls_w[50,1024]^T + cls_b.
// (R10-exact: 3 products; cls is tiny, keep full precision.)
__global__ __launch_bounds__(256) void cls_gemm(
    const f16* __restrict__ A, const float* __restrict__ W,
    const float* __restrict__ bias, float* __restrict__ C) {
    __shared__ bf16 Ah[128][72], Al[128][72];
    __shared__ bf16 Wh[64][72], Wl[64][72];
    const int m0 = blockIdx.x * 128;
    const int tid = threadIdx.x;
    const int wave = tid >> 6;
    const int lane = tid & 63;
    const int lrow = lane & 15;
    const int quad = lane >> 4;
    const int msub = wave * 32;

    f32x4 acc[2][4];
#pragma unroll
    for (int i = 0; i < 2; ++i)
#pragma unroll
        for (int j = 0; j < 4; ++j) acc[i][j] = (f32x4){0.f, 0.f, 0.f, 0.f};

    for (int k0 = 0; k0 < 1024; k0 += 64) {
        __syncthreads();
#pragma unroll
        for (int c = 0; c < 4; ++c) {
            int f = c * 256 + tid;
            int row = f >> 3;
            int kc = f & 7;
            split8h(A + (size_t)(m0 + row) * 1024 + k0 + kc * 8,
                    &Ah[row][kc * 8], &Al[row][kc * 8]);
        }
#pragma unroll
        for (int c = 0; c < 2; ++c) {
            int f = c * 256 + tid;
            int row = f >> 3;
            int kc = f & 7;
            int wr = row < NTAGS ? row : NTAGS - 1;
            split8(W + (size_t)wr * 1024 + k0 + kc * 8,
                   &Wh[row][kc * 8], &Wl[row][kc * 8]);
        }
        __syncthreads();
#pragma unroll
        for (int ks = 0; ks < 2; ++ks) {
            short8 ah[2], al[2], bh[4], bl[4];
#pragma unroll
            for (int i = 0; i < 2; ++i) {
                ah[i] = *(const short8*)&Ah[msub + i * 16 + lrow][ks * 32 + quad * 8];
                al[i] = *(const short8*)&Al[msub + i * 16 + lrow][ks * 32 + quad * 8];
            }
#pragma unroll
            for (int j = 0; j < 4; ++j) {
                bh[j] = *(const short8*)&Wh[j * 16 + lrow][ks * 32 + quad * 8];
                bl[j] = *(const short8*)&Wl[j * 16 + lrow][ks * 32 + quad * 8];
            }
#pragma unroll
            for (int i = 0; i < 2; ++i)
#pragma unroll
                for (int j = 0; j < 4; ++j) {
                    acc[i][j] = __builtin_amdgcn_mfma_f32_16x16x32_bf16(ah[i], bh[j], acc[i][j], 0, 0, 0);
                    acc[i][j] = __builtin_amdgcn_mfma_f32_16x16x32_bf16(ah[i], bl[j], acc[i][j], 0, 0, 0);
                    acc[i][j] = __builtin_amdgcn_mfma_f32_16x16x32_bf16(al[i], bh[j], acc[i][j], 0, 0, 0);
                }
        }
    }

#pragma unroll
    for (int j = 0; j < 4; ++j) {
        int n = j * 16 + lrow;
        if (n < NTAGS) {
            float bv = bias[n];
#pragma unroll
            for (int i = 0; i < 2; ++i)
#pragma unroll
                for (int r = 0; r < 4; ++r) {
                    int m = m0 + msub + i * 16 + quad * 4 + r;
                    C[(size_t)m * NTAGS + n] = acc[i][j][r] + bv;
                }
        }
    }
}

// ---------------------------------------------------------------------------
// Persistent masked BiLSTM scan — R10-EXACT (verified, 1106us/scan).
// h exchanged HI-ONLY; W keeps hi+lo (2 MFMA products).  Protocol: producers
// publish h with sc0sc1 dword stores, drain vmcnt(0), block barrier, tid0
// stores the monotonic per-block flag (relaxed agent, 64B-spaced); consumer
// wave0 polls all 64 flags (one lane each, ballot), barrier releases the
// block, then all waves burst-load h with sc0sc1 dwordx4 + counted vmcnt.
__global__ __launch_bounds__(256, 1) void lstm_scan(
    const f16* __restrict__ xpre_f, const f16* __restrict__ xpre_b,
    const float* __restrict__ whh_f, const float* __restrict__ whh_b,
    const int* __restrict__ lengths,
    f16* __restrict__ out,      // [BT, 2H]
    bf16* __restrict__ hbuf,    // [dir][parity][hi(+unused lo)][64][512]
    int* __restrict__ bar, int base) {
    __shared__ bf16 w_lo2[32][64][8];  // [slot=nt*16+c][lane][8] : lane-private
    __shared__ float gat[64][33];      // [batch][gate*8+u], stride 33
    __shared__ int len_s[64];

    const int dir = blockIdx.x >> 6;
    const int sl = blockIdx.x & 63;
    const int tid = threadIdx.x;
    const int wave = tid >> 6;
    const int lane = tid & 63;
    const int lrow = lane & 15;
    const int quad = lane >> 4;
    // wave-local gate mapping: thread -> (batch gb in wave's 16, unit-pair)
    const int gb = wave * 16 + (lane >> 2);
    const int up = lane & 3;
    const int u0 = up * 2;

    const f16* xpre = dir ? xpre_b : xpre_f;
    const float* whh = dir ? whh_b : whh_f;
    bf16* hb = hbuf + (size_t)dir * 2 * 2 * BB * HH;
    int* flags = bar + dir * 1024;   // 64 single-producer flags, 64B apart
    int* myflag = flags + sl * 16;

    // ---- stage w_hh slice: hi -> regs BH[nt][c], lo -> lane-private LDS.
    short8 BH[2][16];
#pragma unroll
    for (int nt = 0; nt < 2; ++nt) {
        int R = nt * 16 + lrow;
        const float* wr = whh + (size_t)((R >> 3) * HH + sl * 8 + (R & 7)) * HH + quad * 8;
#pragma unroll
        for (int c = 0; c < 16; ++c) {
            float4 v0 = *(const float4*)(wr + c * 32);
            float4 v1 = *(const float4*)(wr + c * 32 + 4);
            float vv[8] = {v0.x, v0.y, v0.z, v0.w, v1.x, v1.y, v1.z, v1.w};
            short8 h8, l8;
#pragma unroll
            for (int j = 0; j < 8; ++j) {
                bf16 h = __float2bfloat16(vv[j]);
                h8[j] = (short)__bfloat16_as_ushort(h);
                l8[j] = f2bs(vv[j] - __bfloat162float(h));
            }
            BH[nt][c] = h8;
            *(short8*)&w_lo2[nt * 16 + c][lane][0] = l8;
        }
    }
    if (tid < 64) len_s[tid] = lengths[tid];
    __syncthreads();

    // persistent per-thread recurrent state (2 hidden units each)
    float hr0 = 0.f, hr1 = 0.f, cr0 = 0.f, cr1 = 0.f;

    // prefetch xpre for s = 0 (len >= 1 always)
    float pr[2][4];
    {
        int len = len_s[gb];
        int ta = dir ? (len - 1) : 0;
        const f16* xp = xpre + (size_t)(gb * TT + ta) * 2048 + sl * 8 + u0;
        half2v g0 = *(const half2v*)(xp);
        half2v g1 = *(const half2v*)(xp + 512);
        half2v g2 = *(const half2v*)(xp + 1024);
        half2v g3 = *(const half2v*)(xp + 1536);
        pr[0][0] = (float)g0[0]; pr[1][0] = (float)g0[1];
        pr[0][1] = (float)g1[0]; pr[1][1] = (float)g1[1];
        pr[0][2] = (float)g2[0]; pr[1][2] = (float)g2[1];
        pr[0][3] = (float)g3[0]; pr[1][3] = (float)g3[1];
    }

    for (int s = 0; s < TT; ++s) {
        if (s > 0) {
            const int target = base + s;

            // ---- wave0-only readiness poll; barrier releases the block
            if (wave == 0) {
                int* fp = &flags[lane * 16];
                int v = __hip_atomic_load(fp, __ATOMIC_RELAXED,
                                          __HIP_MEMORY_SCOPE_AGENT);
                while (__ballot(v >= target) != ~0ull) {
                    __builtin_amdgcn_s_sleep(1);
                    v = __hip_atomic_load(fp, __ATOMIC_RELAXED,
                                          __HIP_MEMORY_SCOPE_AGENT);
                }
            }
            __syncthreads();
            __asm__ volatile("" ::: "memory");

            // ---- burst-issue h-hi loads: 16 x dwordx4, sc0 sc1
            const int b = wave * 16 + lrow;
            const char* hpb = (const char*)hb +
                (size_t)(((s & 1) ^ 1) * 2) * BB * HH * sizeof(bf16);
            const char* hib = hpb + b * 1024 + quad * 16;

            short8 AH[16];
#pragma unroll
            for (int c = 0; c < 16; ++c) {
                asm volatile("global_load_dwordx4 %0, %1, off offset:%2 sc0 sc1"
                             : "=v"(AH[c]) : "v"(hib), "n"(c * 64));
            }

            // 4 accumulator chains: (nt, c&1)
            f32x4 ac[2][2];
            ac[0][0] = (f32x4){0.f, 0.f, 0.f, 0.f};
            ac[0][1] = (f32x4){0.f, 0.f, 0.f, 0.f};
            ac[1][0] = (f32x4){0.f, 0.f, 0.f, 0.f};
            ac[1][1] = (f32x4){0.f, 0.f, 0.f, 0.f};

            // first half ready at vmcnt(8) (in-order completion counting)
            asm volatile("s_waitcnt vmcnt(8)" ::: "memory");
            __builtin_amdgcn_sched_barrier(0);
#pragma unroll
            for (int c = 0; c < 8; ++c) {
#pragma unroll
                for (int nt = 0; nt < 2; ++nt) {
                    short8 bll = *(const short8*)&w_lo2[nt * 16 + c][lane][0];
                    ac[nt][c & 1] = __builtin_amdgcn_mfma_f32_16x16x32_bf16(AH[c], BH[nt][c], ac[nt][c & 1], 0, 0, 0);
                    ac[nt][c & 1] = __builtin_amdgcn_mfma_f32_16x16x32_bf16(AH[c], bll, ac[nt][c & 1], 0, 0, 0);
                }
            }
            asm volatile("s_waitcnt vmcnt(0)" ::: "memory");
            __builtin_amdgcn_sched_barrier(0);
#pragma unroll
            for (int c = 8; c < 16; ++c) {
#pragma unroll
                for (int nt = 0; nt < 2; ++nt) {
                    short8 bll = *(const short8*)&w_lo2[nt * 16 + c][lane][0];
                    ac[nt][c & 1] = __builtin_amdgcn_mfma_f32_16x16x32_bf16(AH[c], BH[nt][c], ac[nt][c & 1], 0, 0, 0);
                    ac[nt][c & 1] = __builtin_amdgcn_mfma_f32_16x16x32_bf16(AH[c], bll, ac[nt][c & 1], 0, 0, 0);
                }
            }
            // acc -> gat (wave-local rows only); rule #18 fence, no barrier.
#pragma unroll
            for (int nt = 0; nt < 2; ++nt)
#pragma unroll
                for (int r = 0; r < 4; ++r)
                    gat[wave * 16 + quad * 4 + r][nt * 16 + lrow] =
                        ac[nt][0][r] + ac[nt][1][r];
            asm volatile("s_waitcnt lgkmcnt(0)" ::: "memory");
            __builtin_amdgcn_sched_barrier(0);
        }

        // ---- gate phase: thread handles (gb, units u0,u0+1), wave-local ----
        const int len = len_s[gb];
        const bool act = (s < len);
        if (act) {
            float z0[4], z1[4];
#pragma unroll
            for (int g = 0; g < 4; ++g) { z0[g] = pr[0][g]; z1[g] = pr[1][g]; }
            if (s > 0) {
#pragma unroll
                for (int g = 0; g < 4; ++g) {
                    z0[g] += gat[gb][g * 8 + u0];
                    z1[g] += gat[gb][g * 8 + u0 + 1];
                }
            }
            float i0 = sigm(z0[0]), f0 = sigm(z0[1]);
            float g0 = tanh_f(z0[2]), o0 = sigm(z0[3]);
            float i1 = sigm(z1[0]), f1 = sigm(z1[1]);
            float g1 = tanh_f(z1[2]), o1 = sigm(z1[3]);
            cr0 = f0 * cr0 + i0 * g0;
            cr1 = f1 * cr1 + i1 * g1;
            hr0 = o0 * tanh_f(cr0);
            hr1 = o1 * tanh_f(cr1);
        }
        // publish h-hi packed (always; carried h for masked rows): 4B sc0sc1
        {
            bf16 bh0 = __float2bfloat16(hr0);
            bf16 bh1 = __float2bfloat16(hr1);
            unsigned int hw = (unsigned int)__bfloat16_as_ushort(bh0) |
                              ((unsigned int)__bfloat16_as_ushort(bh1) << 16);
            char* hcb = (char*)hb + (size_t)((s & 1) * 2) * BB * HH * sizeof(bf16);
            char* pa = hcb + gb * 1024 + (sl * 8 + u0) * 2;
            asm volatile("global_store_dword %0, %1, off sc0 sc1"
                         :: "v"(pa), "v"(hw) : "memory");
        }
        asm volatile("s_waitcnt vmcnt(0)" ::: "memory");  // drain h-stores
        __syncthreads();

        // signal: one fire-and-forget monotonic atomic STORE per block
        if (tid == 0)
            __hip_atomic_store(myflag, base + s + 1, __ATOMIC_RELAXED,
                               __HIP_MEMORY_SCOPE_AGENT);

        // off the inter-block critical path: prefetch next xpre, then out store
        if (s + 1 < TT) {
            if (s + 1 < len) {
                int ta = dir ? (len - 2 - s) : (s + 1);
                const f16* xp = xpre + (size_t)(gb * TT + ta) * 2048 + sl * 8 + u0;
                half2v g0 = *(const half2v*)(xp);
                half2v g1 = *(const half2v*)(xp + 512);
                half2v g2 = *(const half2v*)(xp + 1024);
                half2v g3 = *(const half2v*)(xp + 1536);
                pr[0][0] = (float)g0[0]; pr[1][0] = (float)g0[1];
                pr[0][1] = (float)g1[0]; pr[1][1] = (float)g1[1];
                pr[0][2] = (float)g2[0]; pr[1][2] = (float)g2[1];
                pr[0][3] = (float)g3[0]; pr[1][3] = (float)g3[1];
            }
        }
        if (act) {
            int ta = dir ? (len - 1 - s) : s;
            half2v ov; ov[0] = (f16)hr0; ov[1] = (f16)hr1;
            *(half2v*)(out + (size_t)(gb * TT + ta) * 1024 + dir * 512 + sl * 8 + u0) = ov;
        } else {
            half2v zv; zv[0] = (f16)0.f; zv[1] = (f16)0.f;
            *(half2v*)(out + (size_t)(gb * TT + s) * 1024 + dir * 512 + sl * 8 + u0) = zv;
        }
    }
}

// ---------------------------------------------------------------------------
extern "C" void kernel_launch(void* const* d_in, const int* in_sizes, int n_in,
                              void* d_out, int out_size, void* d_ws, size_t ws_size,
                              hipStream_t stream) {
    const int* x = (const int*)d_in[0];
    const int* lengths = (const int*)d_in[1];
    const float* emb = (const float*)d_in[2];
    const float* w_ih_f1 = (const float*)d_in[3];
    const float* w_hh_f1 = (const float*)d_in[4];
    const float* b_f1 = (const float*)d_in[5];
    const float* w_ih_b1 = (const float*)d_in[6];
    const float* w_hh_b1 = (const float*)d_in[7];
    const float* b_b1 = (const float*)d_in[8];
    const float* w_ih_f2 = (const float*)d_in[9];
    const float* w_hh_f2 = (const float*)d_in[10];
    const float* b_f2 = (const float*)d_in[11];
    const float* w_ih_b2 = (const float*)d_in[12];
    const float* w_hh_b2 = (const float*)d_in[13];
    const float* b_b2 = (const float*)d_in[14];
    const float* cls_w = (const float*)d_in[15];
    const float* cls_b = (const float*)d_in[16];
    float* logits = (float*)d_out;

    // workspace layout (bytes) — max touched offset ~176 MB (proven envelope)
    char* ws = (char*)d_ws;
    int* bar = (int*)ws;                        // 0 .. 8 KB (2x64 flags, 64B apart)
    bf16* hbuf = (bf16*)(ws + 16384);           // 16 KB .. ~1.06 MB
    f16* xpre_f = (f16*)(ws + 16777216);        // 16 MB .. 80 MB
    f16* xpre_b = (f16*)(ws + 83886080);        // 80 MB .. 144 MB
    f16* out1 = (f16*)(ws + 150994944);         // 144 MB .. 176 MB
    f16* out2 = out1;  // alias: out1 dead once layer-2 GEMMs complete

    bar_init<<<8, 256, 0, stream>>>(bar);

    dim3 g1(BT / 128, 2048 / 128);
    gemm_emb<<<g1, 256, 0, stream>>>(x, emb, w_ih_f1, b_f1, xpre_f);
    gemm_emb<<<g1, 256, 0, stream>>>(x, emb, w_ih_b1, b_b1, xpre_b);
    lstm_scan<<<128, 256, 0, stream>>>(xpre_f, xpre_b, w_hh_f1, w_hh_b1,
                                       lengths, out1, hbuf, bar, 0);

    gemm_l2<<<g1, 256, 0, stream>>>(out1, w_ih_f2, b_f2, xpre_f);
    gemm_l2<<<g1, 256, 0, stream>>>(out1, w_ih_b2, b_b2, xpre_b);
    lstm_scan<<<128, 256, 0, stream>>>(xpre_f, xpre_b, w_hh_f2, w_hh_b2,
                                       lengths, out2, hbuf, bar, TT);

    cls_gemm<<<BT / 128, 256, 0, stream>>>(out2, cls_w, cls_b, logits);
}

// Round 12
// 2677.279 us; speedup vs baseline: 1.5363x; 1.0701x over previous
//
#include <hip/hip_runtime.h>
#include <hip/hip_bf16.h>

// Problem constants
#define BB 64
#define TT 256
#define HH 512
#define EE 256
#define NTAGS 50
#define BT (BB * TT)  // 16384

typedef _Float16 f16;
typedef __attribute__((ext_vector_type(2))) _Float16 half2v;
typedef __attribute__((ext_vector_type(4))) _Float16 half4;
typedef __attribute__((ext_vector_type(8))) _Float16 half8;
typedef __attribute__((ext_vector_type(8))) short short8;
typedef __attribute__((ext_vector_type(4))) float f32x4;
typedef __hip_bfloat16 bf16;

__device__ __forceinline__ float sigm(float x) {
    return 1.f / (1.f + __expf(-x));
}
__device__ __forceinline__ float tanh_f(float x) {
    float ax = fabsf(x);
    float e = __expf(2.f * ax);
    float t = 1.f - 2.f / (e + 1.f);
    return x < 0.f ? -t : t;
}
__device__ __forceinline__ short f2bs(float f) {
    return (short)__bfloat16_as_ushort(__float2bfloat16(f));
}
// split 8 fp32 values (in regs) into bf16 hi + bf16 lo(residual)
__device__ __forceinline__ void split8v(const float* vv, bf16* hi, bf16* lo) {
    short8 h8, l8;
#pragma unroll
    for (int j = 0; j < 8; ++j) {
        bf16 h = __float2bfloat16(vv[j]);
        h8[j] = (short)__bfloat16_as_ushort(h);
        l8[j] = f2bs(vv[j] - __bfloat162float(h));
    }
    *(short8*)hi = h8;
    *(short8*)lo = l8;
}
__device__ __forceinline__ void split8(const float* p, bf16* hi, bf16* lo) {
    float4 v0 = *(const float4*)p;
    float4 v1 = *(const float4*)(p + 4);
    float vv[8] = {v0.x, v0.y, v0.z, v0.w, v1.x, v1.y, v1.z, v1.w};
    split8v(vv, hi, lo);
}
__device__ __forceinline__ void split8h(const f16* p, bf16* hi, bf16* lo) {
    half8 a = *(const half8*)p;
    float vv[8];
#pragma unroll
    for (int j = 0; j < 8; ++j) vv[j] = (float)a[j];
    split8v(vv, hi, lo);
}
// f16 -> bf16 hi only (no residual): for A-hi-only layer-2 staging
__device__ __forceinline__ void cvt8h(const f16* p, bf16* hi) {
    half8 a = *(const half8*)p;
    short8 h8;
#pragma unroll
    for (int j = 0; j < 8; ++j)
        h8[j] = (short)__bfloat16_as_ushort(__float2bfloat16((float)a[j]));
    *(short8*)hi = h8;
}

// ---------------------------------------------------------------------------
// 2 dirs x 512 per-(wave,slice) flags x 16-int (64B) spacing = 64KB
__global__ void bar_init(int* __restrict__ bar) {
    bar[blockIdx.x * 256 + threadIdx.x] = 0;
}

// ---------------------------------------------------------------------------
// FUSED embed + layer-1 GEMM (R11-verified):
// C[BT,2048] = emb[x][BT,256] @ W[2048,256]^T + bias.  A gathered straight
// from fp32 emb rows (exact hi/lo split); 3 MFMA products.
__global__ __launch_bounds__(256) void gemm_emb(
    const int* __restrict__ x, const float* __restrict__ emb,
    const float* __restrict__ W, const float* __restrict__ bias,
    f16* __restrict__ C) {
    __shared__ bf16 Ah[128][72], Al[128][72];
    __shared__ bf16 Wh[128][72], Wl[128][72];
    const int m0 = blockIdx.x * 128;
    const int n0 = blockIdx.y * 128;
    const int tid = threadIdx.x;
    const int wave = tid >> 6;
    const int lane = tid & 63;
    const int lrow = lane & 15;
    const int quad = lane >> 4;
    const int msub = (wave >> 1) * 64;
    const int nsub = (wave & 1) * 64;

    int tok[4];
#pragma unroll
    for (int c = 0; c < 4; ++c)
        tok[c] = x[m0 + ((c * 256 + tid) >> 3)];

    f32x4 acc[4][4];
#pragma unroll
    for (int i = 0; i < 4; ++i)
#pragma unroll
        for (int j = 0; j < 4; ++j) acc[i][j] = (f32x4){0.f, 0.f, 0.f, 0.f};

    for (int k0 = 0; k0 < EE; k0 += 64) {
        __syncthreads();
#pragma unroll
        for (int c = 0; c < 4; ++c) {
            int f = c * 256 + tid;
            int row = f >> 3;
            int kc = f & 7;
            split8(emb + (size_t)tok[c] * EE + k0 + kc * 8,
                   &Ah[row][kc * 8], &Al[row][kc * 8]);
            split8(W + (size_t)(n0 + row) * EE + k0 + kc * 8,
                   &Wh[row][kc * 8], &Wl[row][kc * 8]);
        }
        __syncthreads();
#pragma unroll
        for (int ks = 0; ks < 2; ++ks) {
            short8 ah[4], al[4], bh[4], bl[4];
#pragma unroll
            for (int i = 0; i < 4; ++i) {
                ah[i] = *(const short8*)&Ah[msub + i * 16 + lrow][ks * 32 + quad * 8];
                al[i] = *(const short8*)&Al[msub + i * 16 + lrow][ks * 32 + quad * 8];
            }
#pragma unroll
            for (int j = 0; j < 4; ++j) {
                bh[j] = *(const short8*)&Wh[nsub + j * 16 + lrow][ks * 32 + quad * 8];
                bl[j] = *(const short8*)&Wl[nsub + j * 16 + lrow][ks * 32 + quad * 8];
            }
#pragma unroll
            for (int i = 0; i < 4; ++i)
#pragma unroll
                for (int j = 0; j < 4; ++j) {
                    acc[i][j] = __builtin_amdgcn_mfma_f32_16x16x32_bf16(ah[i], bh[j], acc[i][j], 0, 0, 0);
                    acc[i][j] = __builtin_amdgcn_mfma_f32_16x16x32_bf16(ah[i], bl[j], acc[i][j], 0, 0, 0);
                    acc[i][j] = __builtin_amdgcn_mfma_f32_16x16x32_bf16(al[i], bh[j], acc[i][j], 0, 0, 0);
                }
        }
    }

#pragma unroll
    for (int j = 0; j < 4; ++j) {
        int n = n0 + nsub + j * 16 + lrow;
        float bv = bias[n];
#pragma unroll
        for (int i = 0; i < 4; ++i)
#pragma unroll
            for (int r = 0; r < 4; ++r) {
                int m = m0 + msub + i * 16 + quad * 4 + r;
                C[(size_t)m * 2048 + n] = (f16)(acc[i][j][r] + bv);
            }
    }
}

// ---------------------------------------------------------------------------
// Layer-2 GEMM (R11-verified): A bf16-HI-ONLY, W hi+lo -> 2 MFMA products.
__global__ __launch_bounds__(256) void gemm_l2(
    const f16* __restrict__ A, const float* __restrict__ W,
    const float* __restrict__ bias, f16* __restrict__ C) {
    __shared__ bf16 Ah[128][72];
    __shared__ bf16 Wh[128][72], Wl[128][72];
    const int m0 = blockIdx.x * 128;
    const int n0 = blockIdx.y * 128;
    const int tid = threadIdx.x;
    const int wave = tid >> 6;
    const int lane = tid & 63;
    const int lrow = lane & 15;
    const int quad = lane >> 4;
    const int msub = (wave >> 1) * 64;
    const int nsub = (wave & 1) * 64;

    f32x4 acc[4][4];
#pragma unroll
    for (int i = 0; i < 4; ++i)
#pragma unroll
        for (int j = 0; j < 4; ++j) acc[i][j] = (f32x4){0.f, 0.f, 0.f, 0.f};

    for (int k0 = 0; k0 < 1024; k0 += 64) {
        __syncthreads();
#pragma unroll
        for (int c = 0; c < 4; ++c) {
            int f = c * 256 + tid;
            int row = f >> 3;
            int kc = f & 7;
            cvt8h(A + (size_t)(m0 + row) * 1024 + k0 + kc * 8, &Ah[row][kc * 8]);
            split8(W + (size_t)(n0 + row) * 1024 + k0 + kc * 8,
                   &Wh[row][kc * 8], &Wl[row][kc * 8]);
        }
        __syncthreads();
#pragma unroll
        for (int ks = 0; ks < 2; ++ks) {
            short8 ah[4], bh[4], bl[4];
#pragma unroll
            for (int i = 0; i < 4; ++i)
                ah[i] = *(const short8*)&Ah[msub + i * 16 + lrow][ks * 32 + quad * 8];
#pragma unroll
            for (int j = 0; j < 4; ++j) {
                bh[j] = *(const short8*)&Wh[nsub + j * 16 + lrow][ks * 32 + quad * 8];
                bl[j] = *(const short8*)&Wl[nsub + j * 16 + lrow][ks * 32 + quad * 8];
            }
#pragma unroll
            for (int i = 0; i < 4; ++i)
#pragma unroll
                for (int j = 0; j < 4; ++j) {
                    acc[i][j] = __builtin_amdgcn_mfma_f32_16x16x32_bf16(ah[i], bh[j], acc[i][j], 0, 0, 0);
                    acc[i][j] = __builtin_amdgcn_mfma_f32_16x16x32_bf16(ah[i], bl[j], acc[i][j], 0, 0, 0);
                }
        }
    }

#pragma unroll
    for (int j = 0; j < 4; ++j) {
        int n = n0 + nsub + j * 16 + lrow;
        float bv = bias[n];
#pragma unroll
        for (int i = 0; i < 4; ++i)
#pragma unroll
            for (int r = 0; r < 4; ++r) {
                int m = m0 + msub + i * 16 + quad * 4 + r;
                C[(size_t)m * 2048 + n] = (f16)(acc[i][j][r] + bv);
            }
    }
}

// ---------------------------------------------------------------------------
// Classifier (R11-exact): 3 products, full precision.
__global__ __launch_bounds__(256) void cls_gemm(
    const f16* __restrict__ A, const float* __restrict__ W,
    const float* __restrict__ bias, float* __restrict__ C) {
    __shared__ bf16 Ah[128][72], Al[128][72];
    __shared__ bf16 Wh[64][72], Wl[64][72];
    const int m0 = blockIdx.x * 128;
    const int tid = threadIdx.x;
    const int wave = tid >> 6;
    const int lane = tid & 63;
    const int lrow = lane & 15;
    const int quad = lane >> 4;
    const int msub = wave * 32;

    f32x4 acc[2][4];
#pragma unroll
    for (int i = 0; i < 2; ++i)
#pragma unroll
        for (int j = 0; j < 4; ++j) acc[i][j] = (f32x4){0.f, 0.f, 0.f, 0.f};

    for (int k0 = 0; k0 < 1024; k0 += 64) {
        __syncthreads();
#pragma unroll
        for (int c = 0; c < 4; ++c) {
            int f = c * 256 + tid;
            int row = f >> 3;
            int kc = f & 7;
            split8h(A + (size_t)(m0 + row) * 1024 + k0 + kc * 8,
                    &Ah[row][kc * 8], &Al[row][kc * 8]);
        }
#pragma unroll
        for (int c = 0; c < 2; ++c) {
            int f = c * 256 + tid;
            int row = f >> 3;
            int kc = f & 7;
            int wr = row < NTAGS ? row : NTAGS - 1;
            split8(W + (size_t)wr * 1024 + k0 + kc * 8,
                   &Wh[row][kc * 8], &Wl[row][kc * 8]);
        }
        __syncthreads();
#pragma unroll
        for (int ks = 0; ks < 2; ++ks) {
            short8 ah[2], al[2], bh[4], bl[4];
#pragma unroll
            for (int i = 0; i < 2; ++i) {
                ah[i] = *(const short8*)&Ah[msub + i * 16 + lrow][ks * 32 + quad * 8];
                al[i] = *(const short8*)&Al[msub + i * 16 + lrow][ks * 32 + quad * 8];
            }
#pragma unroll
            for (int j = 0; j < 4; ++j) {
                bh[j] = *(const short8*)&Wh[j * 16 + lrow][ks * 32 + quad * 8];
                bl[j] = *(const short8*)&Wl[j * 16 + lrow][ks * 32 + quad * 8];
            }
#pragma unroll
            for (int i = 0; i < 2; ++i)
#pragma unroll
                for (int j = 0; j < 4; ++j) {
                    acc[i][j] = __builtin_amdgcn_mfma_f32_16x16x32_bf16(ah[i], bh[j], acc[i][j], 0, 0, 0);
                    acc[i][j] = __builtin_amdgcn_mfma_f32_16x16x32_bf16(ah[i], bl[j], acc[i][j], 0, 0, 0);
                    acc[i][j] = __builtin_amdgcn_mfma_f32_16x16x32_bf16(al[i], bh[j], acc[i][j], 0, 0, 0);
                }
        }
    }

#pragma unroll
    for (int j = 0; j < 4; ++j) {
        int n = j * 16 + lrow;
        if (n < NTAGS) {
            float bv = bias[n];
#pragma unroll
            for (int i = 0; i < 2; ++i)
#pragma unroll
                for (int r = 0; r < 4; ++r) {
                    int m = m0 + msub + i * 16 + quad * 4 + r;
                    C[(size_t)m * NTAGS + n] = acc[i][j][r] + bv;
                }
        }
    }
}

// ---------------------------------------------------------------------------
// Persistent masked BiLSTM scan — WAVE-AUTONOMOUS protocol (finer-grained
// strict refinement of the R10/R11-verified one).
//
// Key structural fact: waves of a block are fully independent.  Consumer
// wave w loads only h rows [w*16, w*16+16) (its A-fragment batches); the
// producer of those rows, across all 64 blocks of the direction, is always
// wave w (gb = wave*16 + ...).  gat is wave-local (R5), w_lo2/len_s
// read-only after init.  So:
//  - flags are per-(wave,slice): 512/dir, 64B-spaced (R5's proven layout);
//    flag(dir,w,sl) at bar + dir*8192 + (w*64+sl)*16.
//  - EVERY wave polls its own 64-flag dependency group [w*64 + 0..63]
//    (one lane per flag, ballot — exact R5 shape), no barrier.
//  - each wave publishes its 16 rows, drains ITS stores (vmcnt is
//    per-wave), lane0 fires its flag.  BOTH in-loop __syncthreads removed.
//
// Safety (per-wave induction, same as before): wave reaches its step-(s+1)
// write of parity (s+1)&1 only after its poll saw all same-w flags >=
// base+s+1, i.e. every reader of those rows published step s, which (data
// dependency: loads -> MFMA -> publish value) implies its step-s reads of
// parity (s+1)&1 completed.  Flag seen => data at LLC (per-wave vmcnt(0)
// drain precedes the flag store in program order).
__global__ __launch_bounds__(256, 1) void lstm_scan(
    const f16* __restrict__ xpre_f, const f16* __restrict__ xpre_b,
    const float* __restrict__ whh_f, const float* __restrict__ whh_b,
    const int* __restrict__ lengths,
    f16* __restrict__ out,      // [BT, 2H]
    bf16* __restrict__ hbuf,    // [dir][parity][hi(+unused lo)][64][512]
    int* __restrict__ bar, int base) {
    __shared__ bf16 w_lo2[32][64][8];  // [slot=nt*16+c][lane][8] : lane-private
    __shared__ float gat[64][33];      // [batch][gate*8+u], stride 33
    __shared__ int len_s[64];

    const int dir = blockIdx.x >> 6;
    const int sl = blockIdx.x & 63;
    const int tid = threadIdx.x;
    const int wave = tid >> 6;
    const int lane = tid & 63;
    const int lrow = lane & 15;
    const int quad = lane >> 4;
    // wave-local gate mapping: thread -> (batch gb in wave's 16, unit-pair)
    const int gb = wave * 16 + (lane >> 2);
    const int up = lane & 3;
    const int u0 = up * 2;

    const f16* xpre = dir ? xpre_b : xpre_f;
    const float* whh = dir ? whh_b : whh_f;
    bf16* hb = hbuf + (size_t)dir * 2 * 2 * BB * HH;
    int* flags = bar + dir * 8192;             // 512 flags, 64B apart
    int* myflag = flags + (wave * 64 + sl) * 16;
    int* pollp = flags + (wave * 64 + lane) * 16;

    // ---- stage w_hh slice: hi -> regs BH[nt][c], lo -> lane-private LDS.
    short8 BH[2][16];
#pragma unroll
    for (int nt = 0; nt < 2; ++nt) {
        int R = nt * 16 + lrow;
        const float* wr = whh + (size_t)((R >> 3) * HH + sl * 8 + (R & 7)) * HH + quad * 8;
#pragma unroll
        for (int c = 0; c < 16; ++c) {
            float4 v0 = *(const float4*)(wr + c * 32);
            float4 v1 = *(const float4*)(wr + c * 32 + 4);
            float vv[8] = {v0.x, v0.y, v0.z, v0.w, v1.x, v1.y, v1.z, v1.w};
            short8 h8, l8;
#pragma unroll
            for (int j = 0; j < 8; ++j) {
                bf16 h = __float2bfloat16(vv[j]);
                h8[j] = (short)__bfloat16_as_ushort(h);
                l8[j] = f2bs(vv[j] - __bfloat162float(h));
            }
            BH[nt][c] = h8;
            *(short8*)&w_lo2[nt * 16 + c][lane][0] = l8;
        }
    }
    if (tid < 64) len_s[tid] = lengths[tid];
    __syncthreads();   // init barrier only (w_lo2/len_s visible to all)

    // persistent per-thread recurrent state (2 hidden units each)
    float hr0 = 0.f, hr1 = 0.f, cr0 = 0.f, cr1 = 0.f;

    // prefetch xpre for s = 0 (len >= 1 always)
    float pr[2][4];
    {
        int len = len_s[gb];
        int ta = dir ? (len - 1) : 0;
        const f16* xp = xpre + (size_t)(gb * TT + ta) * 2048 + sl * 8 + u0;
        half2v g0 = *(const half2v*)(xp);
        half2v g1 = *(const half2v*)(xp + 512);
        half2v g2 = *(const half2v*)(xp + 1024);
        half2v g3 = *(const half2v*)(xp + 1536);
        pr[0][0] = (float)g0[0]; pr[1][0] = (float)g0[1];
        pr[0][1] = (float)g1[0]; pr[1][1] = (float)g1[1];
        pr[0][2] = (float)g2[0]; pr[1][2] = (float)g2[1];
        pr[0][3] = (float)g3[0]; pr[1][3] = (float)g3[1];
    }

    for (int s = 0; s < TT; ++s) {
        if (s > 0) {
            const int target = base + s;

            // ---- per-wave readiness poll of its OWN dependency group
            {
                int v = __hip_atomic_load(pollp, __ATOMIC_RELAXED,
                                          __HIP_MEMORY_SCOPE_AGENT);
                while (__ballot(v >= target) != ~0ull) {
                    __builtin_amdgcn_s_sleep(1);
                    v = __hip_atomic_load(pollp, __ATOMIC_RELAXED,
                                          __HIP_MEMORY_SCOPE_AGENT);
                }
            }
            __asm__ volatile("" ::: "memory");

            // ---- burst-issue this wave's h-hi rows: 16 x dwordx4, sc0 sc1
            const int b = wave * 16 + lrow;
            const char* hpb = (const char*)hb +
                (size_t)(((s & 1) ^ 1) * 2) * BB * HH * sizeof(bf16);
            const char* hib = hpb + b * 1024 + quad * 16;

            short8 AH[16];
#pragma unroll
            for (int c = 0; c < 16; ++c) {
                asm volatile("global_load_dwordx4 %0, %1, off offset:%2 sc0 sc1"
                             : "=v"(AH[c]) : "v"(hib), "n"(c * 64));
            }

            // 4 accumulator chains: (nt, c&1)
            f32x4 ac[2][2];
            ac[0][0] = (f32x4){0.f, 0.f, 0.f, 0.f};
            ac[0][1] = (f32x4){0.f, 0.f, 0.f, 0.f};
            ac[1][0] = (f32x4){0.f, 0.f, 0.f, 0.f};
            ac[1][1] = (f32x4){0.f, 0.f, 0.f, 0.f};

            // first half ready at vmcnt(8) (in-order completion counting)
            asm volatile("s_waitcnt vmcnt(8)" ::: "memory");
            __builtin_amdgcn_sched_barrier(0);
#pragma unroll
            for (int c = 0; c < 8; ++c) {
#pragma unroll
                for (int nt = 0; nt < 2; ++nt) {
                    short8 bll = *(const short8*)&w_lo2[nt * 16 + c][lane][0];
                    ac[nt][c & 1] = __builtin_amdgcn_mfma_f32_16x16x32_bf16(AH[c], BH[nt][c], ac[nt][c & 1], 0, 0, 0);
                    ac[nt][c & 1] = __builtin_amdgcn_mfma_f32_16x16x32_bf16(AH[c], bll, ac[nt][c & 1], 0, 0, 0);
                }
            }
            asm volatile("s_waitcnt vmcnt(0)" ::: "memory");
            __builtin_amdgcn_sched_barrier(0);
#pragma unroll
            for (int c = 8; c < 16; ++c) {
#pragma unroll
                for (int nt = 0; nt < 2; ++nt) {
                    short8 bll = *(const short8*)&w_lo2[nt * 16 + c][lane][0];
                    ac[nt][c & 1] = __builtin_amdgcn_mfma_f32_16x16x32_bf16(AH[c], BH[nt][c], ac[nt][c & 1], 0, 0, 0);
                    ac[nt][c & 1] = __builtin_amdgcn_mfma_f32_16x16x32_bf16(AH[c], bll, ac[nt][c & 1], 0, 0, 0);
                }
            }
            // acc -> gat (wave-local rows only); rule #18 fence, no barrier.
#pragma unroll
            for (int nt = 0; nt < 2; ++nt)
#pragma unroll
                for (int r = 0; r < 4; ++r)
                    gat[wave * 16 + quad * 4 + r][nt * 16 + lrow] =
                        ac[nt][0][r] + ac[nt][1][r];
            asm volatile("s_waitcnt lgkmcnt(0)" ::: "memory");
            __builtin_amdgcn_sched_barrier(0);
        }

        // ---- gate phase: thread handles (gb, units u0,u0+1), wave-local ----
        const int len = len_s[gb];
        const bool act = (s < len);
        if (act) {
            float z0[4], z1[4];
#pragma unroll
            for (int g = 0; g < 4; ++g) { z0[g] = pr[0][g]; z1[g] = pr[1][g]; }
            if (s > 0) {
#pragma unroll
                for (int g = 0; g < 4; ++g) {
                    z0[g] += gat[gb][g * 8 + u0];
                    z1[g] += gat[gb][g * 8 + u0 + 1];
                }
            }
            float i0 = sigm(z0[0]), f0 = sigm(z0[1]);
            float g0 = tanh_f(z0[2]), o0 = sigm(z0[3]);
            float i1 = sigm(z1[0]), f1 = sigm(z1[1]);
            float g1 = tanh_f(z1[2]), o1 = sigm(z1[3]);
            cr0 = f0 * cr0 + i0 * g0;
            cr1 = f1 * cr1 + i1 * g1;
            hr0 = o0 * tanh_f(cr0);
            hr1 = o1 * tanh_f(cr1);
        }
        // publish h-hi packed (always; carried h for masked rows): 4B sc0sc1
        {
            bf16 bh0 = __float2bfloat16(hr0);
            bf16 bh1 = __float2bfloat16(hr1);
            unsigned int hw = (unsigned int)__bfloat16_as_ushort(bh0) |
                              ((unsigned int)__bfloat16_as_ushort(bh1) << 16);
            char* hcb = (char*)hb + (size_t)((s & 1) * 2) * BB * HH * sizeof(bf16);
            char* pa = hcb + gb * 1024 + (sl * 8 + u0) * 2;
            asm volatile("global_store_dword %0, %1, off sc0 sc1"
                         :: "v"(pa), "v"(hw) : "memory");
        }
        // per-wave drain, then this wave's flag — NO block barrier
        asm volatile("s_waitcnt vmcnt(0)" ::: "memory");
        if (lane == 0)
            __hip_atomic_store(myflag, base + s + 1, __ATOMIC_RELAXED,
                               __HIP_MEMORY_SCOPE_AGENT);

        // off the inter-wave critical path: prefetch next xpre, then out store
        if (s + 1 < TT) {
            if (s + 1 < len) {
                int ta = dir ? (len - 2 - s) : (s + 1);
                const f16* xp = xpre + (size_t)(gb * TT + ta) * 2048 + sl * 8 + u0;
                half2v g0 = *(const half2v*)(xp);
                half2v g1 = *(const half2v*)(xp + 512);
                half2v g2 = *(const half2v*)(xp + 1024);
                half2v g3 = *(const half2v*)(xp + 1536);
                pr[0][0] = (float)g0[0]; pr[1][0] = (float)g0[1];
                pr[0][1] = (float)g1[0]; pr[1][1] = (float)g1[1];
                pr[0][2] = (float)g2[0]; pr[1][2] = (float)g2[1];
                pr[0][3] = (float)g3[0]; pr[1][3] = (float)g3[1];
            }
        }
        if (act) {
            int ta = dir ? (len - 1 - s) : s;
            half2v ov; ov[0] = (f16)hr0; ov[1] = (f16)hr1;
            *(half2v*)(out + (size_t)(gb * TT + ta) * 1024 + dir * 512 + sl * 8 + u0) = ov;
        } else {
            half2v zv; zv[0] = (f16)0.f; zv[1] = (f16)0.f;
            *(half2v*)(out + (size_t)(gb * TT + s) * 1024 + dir * 512 + sl * 8 + u0) = zv;
        }
    }
}

// ---------------------------------------------------------------------------
extern "C" void kernel_launch(void* const* d_in, const int* in_sizes, int n_in,
                              void* d_out, int out_size, void* d_ws, size_t ws_size,
                              hipStream_t stream) {
    const int* x = (const int*)d_in[0];
    const int* lengths = (const int*)d_in[1];
    const float* emb = (const float*)d_in[2];
    const float* w_ih_f1 = (const float*)d_in[3];
    const float* w_hh_f1 = (const float*)d_in[4];
    const float* b_f1 = (const float*)d_in[5];
    const float* w_ih_b1 = (const float*)d_in[6];
    const float* w_hh_b1 = (const float*)d_in[7];
    const float* b_b1 = (const float*)d_in[8];
    const float* w_ih_f2 = (const float*)d_in[9];
    const float* w_hh_f2 = (const float*)d_in[10];
    const float* b_f2 = (const float*)d_in[11];
    const float* w_ih_b2 = (const float*)d_in[12];
    const float* w_hh_b2 = (const float*)d_in[13];
    const float* b_b2 = (const float*)d_in[14];
    const float* cls_w = (const float*)d_in[15];
    const float* cls_b = (const float*)d_in[16];
    float* logits = (float*)d_out;

    // workspace layout (bytes) — max touched offset ~176 MB (proven envelope)
    char* ws = (char*)d_ws;
    int* bar = (int*)ws;                        // 0 .. 64 KB (2x512 flags, 64B apart)
    bf16* hbuf = (bf16*)(ws + 65536);           // 64 KB .. ~1.1 MB
    f16* xpre_f = (f16*)(ws + 16777216);        // 16 MB .. 80 MB
    f16* xpre_b = (f16*)(ws + 83886080);        // 80 MB .. 144 MB
    f16* out1 = (f16*)(ws + 150994944);         // 144 MB .. 176 MB
    f16* out2 = out1;  // alias: out1 dead once layer-2 GEMMs complete

    bar_init<<<64, 256, 0, stream>>>(bar);

    dim3 g1(BT / 128, 2048 / 128);
    gemm_emb<<<g1, 256, 0, stream>>>(x, emb, w_ih_f1, b_f1, xpre_f);
    gemm_emb<<<g1, 256, 0, stream>>>(x, emb, w_ih_b1, b_b1, xpre_b);
    lstm_scan<<<128, 256, 0, stream>>>(xpre_f, xpre_b, w_hh_f1, w_hh_b1,
                                       lengths, out1, hbuf, bar, 0);

    gemm_l2<<<g1, 256, 0, stream>>>(out1, w_ih_f2, b_f2, xpre_f);
    gemm_l2<<<g1, 256, 0, stream>>>(out1, w_ih_b2, b_b2, xpre_b);
    lstm_scan<<<128, 256, 0, stream>>>(xpre_f, xpre_b, w_hh_f2, w_hh_b2,
                                       lengths, out2, hbuf, bar, TT);

    cls_gemm<<<BT / 128, 256, 0, stream>>>(out2, cls_w, cls_b, logits);
}

// Round 13
// 2564.309 us; speedup vs baseline: 1.6040x; 1.0441x over previous
//
#include <hip/hip_runtime.h>
#include <hip/hip_bf16.h>

// Problem constants
#define BB 64
#define TT 256
#define HH 512
#define EE 256
#define NTAGS 50
#define BT (BB * TT)  // 16384

typedef _Float16 f16;
typedef __attribute__((ext_vector_type(2))) _Float16 half2v;
typedef __attribute__((ext_vector_type(4))) _Float16 half4;
typedef __attribute__((ext_vector_type(8))) _Float16 half8;
typedef __attribute__((ext_vector_type(8))) short short8;
typedef __attribute__((ext_vector_type(4))) float f32x4;
typedef __hip_bfloat16 bf16;

__device__ __forceinline__ float sigm(float x) {
    return 1.f / (1.f + __expf(-x));
}
__device__ __forceinline__ float tanh_f(float x) {
    float ax = fabsf(x);
    float e = __expf(2.f * ax);
    float t = 1.f - 2.f / (e + 1.f);
    return x < 0.f ? -t : t;
}
__device__ __forceinline__ short f2bs(float f) {
    return (short)__bfloat16_as_ushort(__float2bfloat16(f));
}
// split 8 fp32 values (in regs) into bf16 hi + bf16 lo(residual)
__device__ __forceinline__ void split8v(const float* vv, bf16* hi, bf16* lo) {
    short8 h8, l8;
#pragma unroll
    for (int j = 0; j < 8; ++j) {
        bf16 h = __float2bfloat16(vv[j]);
        h8[j] = (short)__bfloat16_as_ushort(h);
        l8[j] = f2bs(vv[j] - __bfloat162float(h));
    }
    *(short8*)hi = h8;
    *(short8*)lo = l8;
}
__device__ __forceinline__ void split8(const float* p, bf16* hi, bf16* lo) {
    float4 v0 = *(const float4*)p;
    float4 v1 = *(const float4*)(p + 4);
    float vv[8] = {v0.x, v0.y, v0.z, v0.w, v1.x, v1.y, v1.z, v1.w};
    split8v(vv, hi, lo);
}
__device__ __forceinline__ void split8h(const f16* p, bf16* hi, bf16* lo) {
    half8 a = *(const half8*)p;
    float vv[8];
#pragma unroll
    for (int j = 0; j < 8; ++j) vv[j] = (float)a[j];
    split8v(vv, hi, lo);
}
// f16 -> bf16 hi only (no residual): for A-hi-only layer-2 staging
__device__ __forceinline__ void cvt8h(const f16* p, bf16* hi) {
    half8 a = *(const half8*)p;
    short8 h8;
#pragma unroll
    for (int j = 0; j < 8; ++j)
        h8[j] = (short)__bfloat16_as_ushort(__float2bfloat16((float)a[j]));
    *(short8*)hi = h8;
}

// ---------------------------------------------------------------------------
// 2 dirs x 512 per-(wave,slice) flags x 16-int (64B) spacing = 64KB
__global__ void bar_init(int* __restrict__ bar) {
    bar[blockIdx.x * 256 + threadIdx.x] = 0;
}

// ---------------------------------------------------------------------------
// FUSED embed + layer-1 GEMM (R11-verified) + DEAD-TILE SKIP:
// an M-tile covers batch b = m0>>8, t in [m0&255, (m0&255)+128).  If
// t0 >= len[b] the whole tile is padding — its xpre output is NEVER read
// by the scan (every xpre access is guarded by t < len) -> early return.
__global__ __launch_bounds__(256) void gemm_emb(
    const int* __restrict__ x, const float* __restrict__ emb,
    const float* __restrict__ W, const float* __restrict__ bias,
    const int* __restrict__ lengths, f16* __restrict__ C) {
    const int m0 = blockIdx.x * 128;
    if ((m0 & 255) >= lengths[m0 >> 8]) return;  // fully-dead tile

    __shared__ bf16 Ah[128][72], Al[128][72];
    __shared__ bf16 Wh[128][72], Wl[128][72];
    const int n0 = blockIdx.y * 128;
    const int tid = threadIdx.x;
    const int wave = tid >> 6;
    const int lane = tid & 63;
    const int lrow = lane & 15;
    const int quad = lane >> 4;
    const int msub = (wave >> 1) * 64;
    const int nsub = (wave & 1) * 64;

    int tok[4];
#pragma unroll
    for (int c = 0; c < 4; ++c)
        tok[c] = x[m0 + ((c * 256 + tid) >> 3)];

    f32x4 acc[4][4];
#pragma unroll
    for (int i = 0; i < 4; ++i)
#pragma unroll
        for (int j = 0; j < 4; ++j) acc[i][j] = (f32x4){0.f, 0.f, 0.f, 0.f};

    for (int k0 = 0; k0 < EE; k0 += 64) {
        __syncthreads();
#pragma unroll
        for (int c = 0; c < 4; ++c) {
            int f = c * 256 + tid;
            int row = f >> 3;
            int kc = f & 7;
            split8(emb + (size_t)tok[c] * EE + k0 + kc * 8,
                   &Ah[row][kc * 8], &Al[row][kc * 8]);
            split8(W + (size_t)(n0 + row) * EE + k0 + kc * 8,
                   &Wh[row][kc * 8], &Wl[row][kc * 8]);
        }
        __syncthreads();
#pragma unroll
        for (int ks = 0; ks < 2; ++ks) {
            short8 ah[4], al[4], bh[4], bl[4];
#pragma unroll
            for (int i = 0; i < 4; ++i) {
                ah[i] = *(const short8*)&Ah[msub + i * 16 + lrow][ks * 32 + quad * 8];
                al[i] = *(const short8*)&Al[msub + i * 16 + lrow][ks * 32 + quad * 8];
            }
#pragma unroll
            for (int j = 0; j < 4; ++j) {
                bh[j] = *(const short8*)&Wh[nsub + j * 16 + lrow][ks * 32 + quad * 8];
                bl[j] = *(const short8*)&Wl[nsub + j * 16 + lrow][ks * 32 + quad * 8];
            }
#pragma unroll
            for (int i = 0; i < 4; ++i)
#pragma unroll
                for (int j = 0; j < 4; ++j) {
                    acc[i][j] = __builtin_amdgcn_mfma_f32_16x16x32_bf16(ah[i], bh[j], acc[i][j], 0, 0, 0);
                    acc[i][j] = __builtin_amdgcn_mfma_f32_16x16x32_bf16(ah[i], bl[j], acc[i][j], 0, 0, 0);
                    acc[i][j] = __builtin_amdgcn_mfma_f32_16x16x32_bf16(al[i], bh[j], acc[i][j], 0, 0, 0);
                }
        }
    }

#pragma unroll
    for (int j = 0; j < 4; ++j) {
        int n = n0 + nsub + j * 16 + lrow;
        float bv = bias[n];
#pragma unroll
        for (int i = 0; i < 4; ++i)
#pragma unroll
            for (int r = 0; r < 4; ++r) {
                int m = m0 + msub + i * 16 + quad * 4 + r;
                C[(size_t)m * 2048 + n] = (f16)(acc[i][j][r] + bv);
            }
    }
}

// ---------------------------------------------------------------------------
// Layer-2 GEMM (R11-verified): A bf16-HI-ONLY, W hi+lo -> 2 MFMA products.
// Same dead-tile skip as gemm_emb.
__global__ __launch_bounds__(256) void gemm_l2(
    const f16* __restrict__ A, const float* __restrict__ W,
    const float* __restrict__ bias, const int* __restrict__ lengths,
    f16* __restrict__ C) {
    const int m0 = blockIdx.x * 128;
    if ((m0 & 255) >= lengths[m0 >> 8]) return;  // fully-dead tile

    __shared__ bf16 Ah[128][72];
    __shared__ bf16 Wh[128][72], Wl[128][72];
    const int n0 = blockIdx.y * 128;
    const int tid = threadIdx.x;
    const int wave = tid >> 6;
    const int lane = tid & 63;
    const int lrow = lane & 15;
    const int quad = lane >> 4;
    const int msub = (wave >> 1) * 64;
    const int nsub = (wave & 1) * 64;

    f32x4 acc[4][4];
#pragma unroll
    for (int i = 0; i < 4; ++i)
#pragma unroll
        for (int j = 0; j < 4; ++j) acc[i][j] = (f32x4){0.f, 0.f, 0.f, 0.f};

    for (int k0 = 0; k0 < 1024; k0 += 64) {
        __syncthreads();
#pragma unroll
        for (int c = 0; c < 4; ++c) {
            int f = c * 256 + tid;
            int row = f >> 3;
            int kc = f & 7;
            cvt8h(A + (size_t)(m0 + row) * 1024 + k0 + kc * 8, &Ah[row][kc * 8]);
            split8(W + (size_t)(n0 + row) * 1024 + k0 + kc * 8,
                   &Wh[row][kc * 8], &Wl[row][kc * 8]);
        }
        __syncthreads();
#pragma unroll
        for (int ks = 0; ks < 2; ++ks) {
            short8 ah[4], bh[4], bl[4];
#pragma unroll
            for (int i = 0; i < 4; ++i)
                ah[i] = *(const short8*)&Ah[msub + i * 16 + lrow][ks * 32 + quad * 8];
#pragma unroll
            for (int j = 0; j < 4; ++j) {
                bh[j] = *(const short8*)&Wh[nsub + j * 16 + lrow][ks * 32 + quad * 8];
                bl[j] = *(const short8*)&Wl[nsub + j * 16 + lrow][ks * 32 + quad * 8];
            }
#pragma unroll
            for (int i = 0; i < 4; ++i)
#pragma unroll
                for (int j = 0; j < 4; ++j) {
                    acc[i][j] = __builtin_amdgcn_mfma_f32_16x16x32_bf16(ah[i], bh[j], acc[i][j], 0, 0, 0);
                    acc[i][j] = __builtin_amdgcn_mfma_f32_16x16x32_bf16(ah[i], bl[j], acc[i][j], 0, 0, 0);
                }
        }
    }

#pragma unroll
    for (int j = 0; j < 4; ++j) {
        int n = n0 + nsub + j * 16 + lrow;
        float bv = bias[n];
#pragma unroll
        for (int i = 0; i < 4; ++i)
#pragma unroll
            for (int r = 0; r < 4; ++r) {
                int m = m0 + msub + i * 16 + quad * 4 + r;
                C[(size_t)m * 2048 + n] = (f16)(acc[i][j][r] + bv);
            }
    }
}

// ---------------------------------------------------------------------------
// Classifier (R11 core): 3 products.  DEAD-TILE FAST PATH: padding rows
// have out2 == 0 exactly, so logits = cls_b exactly — write bias, skip the
// K-loop (bit-identical to the full computation for those rows).
__global__ __launch_bounds__(256) void cls_gemm(
    const f16* __restrict__ A, const float* __restrict__ W,
    const float* __restrict__ bias, const int* __restrict__ lengths,
    float* __restrict__ C) {
    const int m0 = blockIdx.x * 128;
    const int tid = threadIdx.x;
    if ((m0 & 255) >= lengths[m0 >> 8]) {
        // bias broadcast: 128 rows x 50 cols
        for (int f = tid; f < 128 * NTAGS; f += 256) {
            int r = f / NTAGS, n = f % NTAGS;
            C[(size_t)(m0 + r) * NTAGS + n] = bias[n];
        }
        return;
    }

    __shared__ bf16 Ah[128][72], Al[128][72];
    __shared__ bf16 Wh[64][72], Wl[64][72];
    const int wave = tid >> 6;
    const int lane = tid & 63;
    const int lrow = lane & 15;
    const int quad = lane >> 4;
    const int msub = wave * 32;

    f32x4 acc[2][4];
#pragma unroll
    for (int i = 0; i < 2; ++i)
#pragma unroll
        for (int j = 0; j < 4; ++j) acc[i][j] = (f32x4){0.f, 0.f, 0.f, 0.f};

    for (int k0 = 0; k0 < 1024; k0 += 64) {
        __syncthreads();
#pragma unroll
        for (int c = 0; c < 4; ++c) {
            int f = c * 256 + tid;
            int row = f >> 3;
            int kc = f & 7;
            split8h(A + (size_t)(m0 + row) * 1024 + k0 + kc * 8,
                    &Ah[row][kc * 8], &Al[row][kc * 8]);
        }
#pragma unroll
        for (int c = 0; c < 2; ++c) {
            int f = c * 256 + tid;
            int row = f >> 3;
            int kc = f & 7;
            int wr = row < NTAGS ? row : NTAGS - 1;
            split8(W + (size_t)wr * 1024 + k0 + kc * 8,
                   &Wh[row][kc * 8], &Wl[row][kc * 8]);
        }
        __syncthreads();
#pragma unroll
        for (int ks = 0; ks < 2; ++ks) {
            short8 ah[2], al[2], bh[4], bl[4];
#pragma unroll
            for (int i = 0; i < 2; ++i) {
                ah[i] = *(const short8*)&Ah[msub + i * 16 + lrow][ks * 32 + quad * 8];
                al[i] = *(const short8*)&Al[msub + i * 16 + lrow][ks * 32 + quad * 8];
            }
#pragma unroll
            for (int j = 0; j < 4; ++j) {
                bh[j] = *(const short8*)&Wh[j * 16 + lrow][ks * 32 + quad * 8];
                bl[j] = *(const short8*)&Wl[j * 16 + lrow][ks * 32 + quad * 8];
            }
#pragma unroll
            for (int i = 0; i < 2; ++i)
#pragma unroll
                for (int j = 0; j < 4; ++j) {
                    acc[i][j] = __builtin_amdgcn_mfma_f32_16x16x32_bf16(ah[i], bh[j], acc[i][j], 0, 0, 0);
                    acc[i][j] = __builtin_amdgcn_mfma_f32_16x16x32_bf16(ah[i], bl[j], acc[i][j], 0, 0, 0);
                    acc[i][j] = __builtin_amdgcn_mfma_f32_16x16x32_bf16(al[i], bh[j], acc[i][j], 0, 0, 0);
                }
        }
    }

#pragma unroll
    for (int j = 0; j < 4; ++j) {
        int n = j * 16 + lrow;
        if (n < NTAGS) {
            float bv = bias[n];
#pragma unroll
            for (int i = 0; i < 2; ++i)
#pragma unroll
                for (int r = 0; r < 4; ++r) {
                    int m = m0 + msub + i * 16 + quad * 4 + r;
                    C[(size_t)m * NTAGS + n] = acc[i][j][r] + bv;
                }
        }
    }
}

// ---------------------------------------------------------------------------
// Persistent masked BiLSTM scan — R12 WAVE-AUTONOMOUS protocol (verified,
// 1022us/scan) + finer MFMA pipelining: 8 accumulator chains (nt, c&3) and
// staged vmcnt(12/8/4/0) so MFMA starts after only 4 of 16 loads land and
// dependent-chain depth halves.  Protocol unchanged: per-(wave,slice)
// flags, per-wave poll/drain/publish, no in-loop block barriers.
__global__ __launch_bounds__(256, 1) void lstm_scan(
    const f16* __restrict__ xpre_f, const f16* __restrict__ xpre_b,
    const float* __restrict__ whh_f, const float* __restrict__ whh_b,
    const int* __restrict__ lengths,
    f16* __restrict__ out,      // [BT, 2H]
    bf16* __restrict__ hbuf,    // [dir][parity][hi(+unused lo)][64][512]
    int* __restrict__ bar, int base) {
    __shared__ bf16 w_lo2[32][64][8];  // [slot=nt*16+c][lane][8] : lane-private
    __shared__ float gat[64][33];      // [batch][gate*8+u], stride 33
    __shared__ int len_s[64];

    const int dir = blockIdx.x >> 6;
    const int sl = blockIdx.x & 63;
    const int tid = threadIdx.x;
    const int wave = tid >> 6;
    const int lane = tid & 63;
    const int lrow = lane & 15;
    const int quad = lane >> 4;
    // wave-local gate mapping: thread -> (batch gb in wave's 16, unit-pair)
    const int gb = wave * 16 + (lane >> 2);
    const int up = lane & 3;
    const int u0 = up * 2;

    const f16* xpre = dir ? xpre_b : xpre_f;
    const float* whh = dir ? whh_b : whh_f;
    bf16* hb = hbuf + (size_t)dir * 2 * 2 * BB * HH;
    int* flags = bar + dir * 8192;             // 512 flags, 64B apart
    int* myflag = flags + (wave * 64 + sl) * 16;
    int* pollp = flags + (wave * 64 + lane) * 16;

    // ---- stage w_hh slice: hi -> regs BH[nt][c], lo -> lane-private LDS.
    short8 BH[2][16];
#pragma unroll
    for (int nt = 0; nt < 2; ++nt) {
        int R = nt * 16 + lrow;
        const float* wr = whh + (size_t)((R >> 3) * HH + sl * 8 + (R & 7)) * HH + quad * 8;
#pragma unroll
        for (int c = 0; c < 16; ++c) {
            float4 v0 = *(const float4*)(wr + c * 32);
            float4 v1 = *(const float4*)(wr + c * 32 + 4);
            float vv[8] = {v0.x, v0.y, v0.z, v0.w, v1.x, v1.y, v1.z, v1.w};
            short8 h8, l8;
#pragma unroll
            for (int j = 0; j < 8; ++j) {
                bf16 h = __float2bfloat16(vv[j]);
                h8[j] = (short)__bfloat16_as_ushort(h);
                l8[j] = f2bs(vv[j] - __bfloat162float(h));
            }
            BH[nt][c] = h8;
            *(short8*)&w_lo2[nt * 16 + c][lane][0] = l8;
        }
    }
    if (tid < 64) len_s[tid] = lengths[tid];
    __syncthreads();   // init barrier only (w_lo2/len_s visible to all)

    // persistent per-thread recurrent state (2 hidden units each)
    float hr0 = 0.f, hr1 = 0.f, cr0 = 0.f, cr1 = 0.f;

    // prefetch xpre for s = 0 (len >= 1 always)
    float pr[2][4];
    {
        int len = len_s[gb];
        int ta = dir ? (len - 1) : 0;
        const f16* xp = xpre + (size_t)(gb * TT + ta) * 2048 + sl * 8 + u0;
        half2v g0 = *(const half2v*)(xp);
        half2v g1 = *(const half2v*)(xp + 512);
        half2v g2 = *(const half2v*)(xp + 1024);
        half2v g3 = *(const half2v*)(xp + 1536);
        pr[0][0] = (float)g0[0]; pr[1][0] = (float)g0[1];
        pr[0][1] = (float)g1[0]; pr[1][1] = (float)g1[1];
        pr[0][2] = (float)g2[0]; pr[1][2] = (float)g2[1];
        pr[0][3] = (float)g3[0]; pr[1][3] = (float)g3[1];
    }

    for (int s = 0; s < TT; ++s) {
        if (s > 0) {
            const int target = base + s;

            // ---- per-wave readiness poll of its OWN dependency group
            {
                int v = __hip_atomic_load(pollp, __ATOMIC_RELAXED,
                                          __HIP_MEMORY_SCOPE_AGENT);
                while (__ballot(v >= target) != ~0ull) {
                    __builtin_amdgcn_s_sleep(1);
                    v = __hip_atomic_load(pollp, __ATOMIC_RELAXED,
                                          __HIP_MEMORY_SCOPE_AGENT);
                }
            }
            __asm__ volatile("" ::: "memory");

            // ---- burst-issue this wave's h-hi rows: 16 x dwordx4, sc0 sc1
            const int b = wave * 16 + lrow;
            const char* hpb = (const char*)hb +
                (size_t)(((s & 1) ^ 1) * 2) * BB * HH * sizeof(bf16);
            const char* hib = hpb + b * 1024 + quad * 16;

            short8 AH[16];
#pragma unroll
            for (int c = 0; c < 16; ++c) {
                asm volatile("global_load_dwordx4 %0, %1, off offset:%2 sc0 sc1"
                             : "=v"(AH[c]) : "v"(hib), "n"(c * 64));
            }

            // 8 accumulator chains: (nt, c&3); staged vmcnt 12/8/4/0
            f32x4 ac[2][4];
#pragma unroll
            for (int nt = 0; nt < 2; ++nt)
#pragma unroll
                for (int q = 0; q < 4; ++q)
                    ac[nt][q] = (f32x4){0.f, 0.f, 0.f, 0.f};

            asm volatile("s_waitcnt vmcnt(12)" ::: "memory");
            __builtin_amdgcn_sched_barrier(0);
#pragma unroll
            for (int c = 0; c < 4; ++c)
#pragma unroll
                for (int nt = 0; nt < 2; ++nt) {
                    short8 bll = *(const short8*)&w_lo2[nt * 16 + c][lane][0];
                    ac[nt][c & 3] = __builtin_amdgcn_mfma_f32_16x16x32_bf16(AH[c], BH[nt][c], ac[nt][c & 3], 0, 0, 0);
                    ac[nt][c & 3] = __builtin_amdgcn_mfma_f32_16x16x32_bf16(AH[c], bll, ac[nt][c & 3], 0, 0, 0);
                }
            asm volatile("s_waitcnt vmcnt(8)" ::: "memory");
            __builtin_amdgcn_sched_barrier(0);
#pragma unroll
            for (int c = 4; c < 8; ++c)
#pragma unroll
                for (int nt = 0; nt < 2; ++nt) {
                    short8 bll = *(const short8*)&w_lo2[nt * 16 + c][lane][0];
                    ac[nt][c & 3] = __builtin_amdgcn_mfma_f32_16x16x32_bf16(AH[c], BH[nt][c], ac[nt][c & 3], 0, 0, 0);
                    ac[nt][c & 3] = __builtin_amdgcn_mfma_f32_16x16x32_bf16(AH[c], bll, ac[nt][c & 3], 0, 0, 0);
                }
            asm volatile("s_waitcnt vmcnt(4)" ::: "memory");
            __builtin_amdgcn_sched_barrier(0);
#pragma unroll
            for (int c = 8; c < 12; ++c)
#pragma unroll
                for (int nt = 0; nt < 2; ++nt) {
                    short8 bll = *(const short8*)&w_lo2[nt * 16 + c][lane][0];
                    ac[nt][c & 3] = __builtin_amdgcn_mfma_f32_16x16x32_bf16(AH[c], BH[nt][c], ac[nt][c & 3], 0, 0, 0);
                    ac[nt][c & 3] = __builtin_amdgcn_mfma_f32_16x16x32_bf16(AH[c], bll, ac[nt][c & 3], 0, 0, 0);
                }
            asm volatile("s_waitcnt vmcnt(0)" ::: "memory");
            __builtin_amdgcn_sched_barrier(0);
#pragma unroll
            for (int c = 12; c < 16; ++c)
#pragma unroll
                for (int nt = 0; nt < 2; ++nt) {
                    short8 bll = *(const short8*)&w_lo2[nt * 16 + c][lane][0];
                    ac[nt][c & 3] = __builtin_amdgcn_mfma_f32_16x16x32_bf16(AH[c], BH[nt][c], ac[nt][c & 3], 0, 0, 0);
                    ac[nt][c & 3] = __builtin_amdgcn_mfma_f32_16x16x32_bf16(AH[c], bll, ac[nt][c & 3], 0, 0, 0);
                }
            // acc -> gat (wave-local rows only); rule #18 fence, no barrier.
#pragma unroll
            for (int nt = 0; nt < 2; ++nt)
#pragma unroll
                for (int r = 0; r < 4; ++r)
                    gat[wave * 16 + quad * 4 + r][nt * 16 + lrow] =
                        (ac[nt][0][r] + ac[nt][1][r]) + (ac[nt][2][r] + ac[nt][3][r]);
            asm volatile("s_waitcnt lgkmcnt(0)" ::: "memory");
            __builtin_amdgcn_sched_barrier(0);
        }

        // ---- gate phase: thread handles (gb, units u0,u0+1), wave-local ----
        const int len = len_s[gb];
        const bool act = (s < len);
        if (act) {
            float z0[4], z1[4];
#pragma unroll
            for (int g = 0; g < 4; ++g) { z0[g] = pr[0][g]; z1[g] = pr[1][g]; }
            if (s > 0) {
#pragma unroll
                for (int g = 0; g < 4; ++g) {
                    z0[g] += gat[gb][g * 8 + u0];
                    z1[g] += gat[gb][g * 8 + u0 + 1];
                }
            }
            float i0 = sigm(z0[0]), f0 = sigm(z0[1]);
            float g0 = tanh_f(z0[2]), o0 = sigm(z0[3]);
            float i1 = sigm(z1[0]), f1 = sigm(z1[1]);
            float g1 = tanh_f(z1[2]), o1 = sigm(z1[3]);
            cr0 = f0 * cr0 + i0 * g0;
            cr1 = f1 * cr1 + i1 * g1;
            hr0 = o0 * tanh_f(cr0);
            hr1 = o1 * tanh_f(cr1);
        }
        // publish h-hi packed (always; carried h for masked rows): 4B sc0sc1
        {
            bf16 bh0 = __float2bfloat16(hr0);
            bf16 bh1 = __float2bfloat16(hr1);
            unsigned int hw = (unsigned int)__bfloat16_as_ushort(bh0) |
                              ((unsigned int)__bfloat16_as_ushort(bh1) << 16);
            char* hcb = (char*)hb + (size_t)((s & 1) * 2) * BB * HH * sizeof(bf16);
            char* pa = hcb + gb * 1024 + (sl * 8 + u0) * 2;
            asm volatile("global_store_dword %0, %1, off sc0 sc1"
                         :: "v"(pa), "v"(hw) : "memory");
        }
        // per-wave drain, then this wave's flag — NO block barrier
        asm volatile("s_waitcnt vmcnt(0)" ::: "memory");
        if (lane == 0)
            __hip_atomic_store(myflag, base + s + 1, __ATOMIC_RELAXED,
                               __HIP_MEMORY_SCOPE_AGENT);

        // off the inter-wave critical path: prefetch next xpre, then out store
        if (s + 1 < TT) {
            if (s + 1 < len) {
                int ta = dir ? (len - 2 - s) : (s + 1);
                const f16* xp = xpre + (size_t)(gb * TT + ta) * 2048 + sl * 8 + u0;
                half2v g0 = *(const half2v*)(xp);
                half2v g1 = *(const half2v*)(xp + 512);
                half2v g2 = *(const half2v*)(xp + 1024);
                half2v g3 = *(const half2v*)(xp + 1536);
                pr[0][0] = (float)g0[0]; pr[1][0] = (float)g0[1];
                pr[0][1] = (float)g1[0]; pr[1][1] = (float)g1[1];
                pr[0][2] = (float)g2[0]; pr[1][2] = (float)g2[1];
                pr[0][3] = (float)g3[0]; pr[1][3] = (float)g3[1];
            }
        }
        if (act) {
            int ta = dir ? (len - 1 - s) : s;
            half2v ov; ov[0] = (f16)hr0; ov[1] = (f16)hr1;
            *(half2v*)(out + (size_t)(gb * TT + ta) * 1024 + dir * 512 + sl * 8 + u0) = ov;
        } else {
            half2v zv; zv[0] = (f16)0.f; zv[1] = (f16)0.f;
            *(half2v*)(out + (size_t)(gb * TT + s) * 1024 + dir * 512 + sl * 8 + u0) = zv;
        }
    }
}

// ---------------------------------------------------------------------------
extern "C" void kernel_launch(void* const* d_in, const int* in_sizes, int n_in,
                              void* d_out, int out_size, void* d_ws, size_t ws_size,
                              hipStream_t stream) {
    const int* x = (const int*)d_in[0];
    const int* lengths = (const int*)d_in[1];
    const float* emb = (const float*)d_in[2];
    const float* w_ih_f1 = (const float*)d_in[3];
    const float* w_hh_f1 = (const float*)d_in[4];
    const float* b_f1 = (const float*)d_in[5];
    const float* w_ih_b1 = (const float*)d_in[6];
    const float* w_hh_b1 = (const float*)d_in[7];
    const float* b_b1 = (const float*)d_in[8];
    const float* w_ih_f2 = (const float*)d_in[9];
    const float* w_hh_f2 = (const float*)d_in[10];
    const float* b_f2 = (const float*)d_in[11];
    const float* w_ih_b2 = (const float*)d_in[12];
    const float* w_hh_b2 = (const float*)d_in[13];
    const float* b_b2 = (const float*)d_in[14];
    const float* cls_w = (const float*)d_in[15];
    const float* cls_b = (const float*)d_in[16];
    float* logits = (float*)d_out;

    // workspace layout (bytes) — max touched offset ~176 MB (proven envelope)
    char* ws = (char*)d_ws;
    int* bar = (int*)ws;                        // 0 .. 64 KB (2x512 flags, 64B apart)
    bf16* hbuf = (bf16*)(ws + 65536);           // 64 KB .. ~1.1 MB
    f16* xpre_f = (f16*)(ws + 16777216);        // 16 MB .. 80 MB
    f16* xpre_b = (f16*)(ws + 83886080);        // 80 MB .. 144 MB
    f16* out1 = (f16*)(ws + 150994944);         // 144 MB .. 176 MB
    f16* out2 = out1;  // alias: out1 dead once layer-2 GEMMs complete

    bar_init<<<64, 256, 0, stream>>>(bar);

    dim3 g1(BT / 128, 2048 / 128);
    gemm_emb<<<g1, 256, 0, stream>>>(x, emb, w_ih_f1, b_f1, lengths, xpre_f);
    gemm_emb<<<g1, 256, 0, stream>>>(x, emb, w_ih_b1, b_b1, lengths, xpre_b);
    lstm_scan<<<128, 256, 0, stream>>>(xpre_f, xpre_b, w_hh_f1, w_hh_b1,
                                       lengths, out1, hbuf, bar, 0);

    gemm_l2<<<g1, 256, 0, stream>>>(out1, w_ih_f2, b_f2, lengths, xpre_f);
    gemm_l2<<<g1, 256, 0, stream>>>(out1, w_ih_b2, b_b2, lengths, xpre_b);
    lstm_scan<<<128, 256, 0, stream>>>(xpre_f, xpre_b, w_hh_f2, w_hh_b2,
                                       lengths, out2, hbuf, bar, TT);

    cls_gemm<<<BT / 128, 256, 0, stream>>>(out2, cls_w, cls_b, lengths, logits);
}

// Round 15
// 2330.191 us; speedup vs baseline: 1.7651x; 1.1005x over previous
//
#include <hip/hip_runtime.h>
#include <hip/hip_bf16.h>

// Problem constants
#define BB 64
#define TT 256
#define HH 512
#define EE 256
#define NTAGS 50
#define BT (BB * TT)  // 16384

typedef _Float16 f16;
typedef __attribute__((ext_vector_type(2))) _Float16 half2v;
typedef __attribute__((ext_vector_type(4))) _Float16 half4;
typedef __attribute__((ext_vector_type(8))) _Float16 half8;
typedef __attribute__((ext_vector_type(8))) short short8;
typedef __attribute__((ext_vector_type(4))) float f32x4;
typedef __hip_bfloat16 bf16;

__device__ __forceinline__ float sigm(float x) {
    return 1.f / (1.f + __expf(-x));
}
__device__ __forceinline__ float tanh_f(float x) {
    float ax = fabsf(x);
    float e = __expf(2.f * ax);
    float t = 1.f - 2.f / (e + 1.f);
    return x < 0.f ? -t : t;
}
__device__ __forceinline__ short f2bs(float f) {
    return (short)__bfloat16_as_ushort(__float2bfloat16(f));
}
// split 8 fp32 values (in regs) into bf16 hi + bf16 lo(residual)
__device__ __forceinline__ void split8v(const float* vv, bf16* hi, bf16* lo) {
    short8 h8, l8;
#pragma unroll
    for (int j = 0; j < 8; ++j) {
        bf16 h = __float2bfloat16(vv[j]);
        h8[j] = (short)__bfloat16_as_ushort(h);
        l8[j] = f2bs(vv[j] - __bfloat162float(h));
    }
    *(short8*)hi = h8;
    *(short8*)lo = l8;
}
__device__ __forceinline__ void split8(const float* p, bf16* hi, bf16* lo) {
    float4 v0 = *(const float4*)p;
    float4 v1 = *(const float4*)(p + 4);
    float vv[8] = {v0.x, v0.y, v0.z, v0.w, v1.x, v1.y, v1.z, v1.w};
    split8v(vv, hi, lo);
}
__device__ __forceinline__ void split8h(const f16* p, bf16* hi, bf16* lo) {
    half8 a = *(const half8*)p;
    float vv[8];
#pragma unroll
    for (int j = 0; j < 8; ++j) vv[j] = (float)a[j];
    split8v(vv, hi, lo);
}
// f16 -> bf16 hi only (no residual): for A-hi-only layer-2 staging
__device__ __forceinline__ void cvt8h(const f16* p, bf16* hi) {
    half8 a = *(const half8*)p;
    short8 h8;
#pragma unroll
    for (int j = 0; j < 8; ++j)
        h8[j] = (short)__bfloat16_as_ushort(__float2bfloat16((float)a[j]));
    *(short8*)hi = h8;
}

// ---------------------------------------------------------------------------
// 2 dirs x 512 per-(wave,slice) flags x 16-int (64B) spacing = 64KB
__global__ void bar_init(int* __restrict__ bar) {
    bar[blockIdx.x * 256 + threadIdx.x] = 0;
}

// ---------------------------------------------------------------------------
// FUSED embed + layer-1 GEMM (R11-verified) + DEAD-TILE SKIP (R13).
__global__ __launch_bounds__(256) void gemm_emb(
    const int* __restrict__ x, const float* __restrict__ emb,
    const float* __restrict__ W, const float* __restrict__ bias,
    const int* __restrict__ lengths, f16* __restrict__ C) {
    const int m0 = blockIdx.x * 128;
    if ((m0 & 255) >= lengths[m0 >> 8]) return;  // fully-dead tile

    __shared__ bf16 Ah[128][72], Al[128][72];
    __shared__ bf16 Wh[128][72], Wl[128][72];
    const int n0 = blockIdx.y * 128;
    const int tid = threadIdx.x;
    const int wave = tid >> 6;
    const int lane = tid & 63;
    const int lrow = lane & 15;
    const int quad = lane >> 4;
    const int msub = (wave >> 1) * 64;
    const int nsub = (wave & 1) * 64;

    int tok[4];
#pragma unroll
    for (int c = 0; c < 4; ++c)
        tok[c] = x[m0 + ((c * 256 + tid) >> 3)];

    f32x4 acc[4][4];
#pragma unroll
    for (int i = 0; i < 4; ++i)
#pragma unroll
        for (int j = 0; j < 4; ++j) acc[i][j] = (f32x4){0.f, 0.f, 0.f, 0.f};

    for (int k0 = 0; k0 < EE; k0 += 64) {
        __syncthreads();
#pragma unroll
        for (int c = 0; c < 4; ++c) {
            int f = c * 256 + tid;
            int row = f >> 3;
            int kc = f & 7;
            split8(emb + (size_t)tok[c] * EE + k0 + kc * 8,
                   &Ah[row][kc * 8], &Al[row][kc * 8]);
            split8(W + (size_t)(n0 + row) * EE + k0 + kc * 8,
                   &Wh[row][kc * 8], &Wl[row][kc * 8]);
        }
        __syncthreads();
#pragma unroll
        for (int ks = 0; ks < 2; ++ks) {
            short8 ah[4], al[4], bh[4], bl[4];
#pragma unroll
            for (int i = 0; i < 4; ++i) {
                ah[i] = *(const short8*)&Ah[msub + i * 16 + lrow][ks * 32 + quad * 8];
                al[i] = *(const short8*)&Al[msub + i * 16 + lrow][ks * 32 + quad * 8];
            }
#pragma unroll
            for (int j = 0; j < 4; ++j) {
                bh[j] = *(const short8*)&Wh[nsub + j * 16 + lrow][ks * 32 + quad * 8];
                bl[j] = *(const short8*)&Wl[nsub + j * 16 + lrow][ks * 32 + quad * 8];
            }
#pragma unroll
            for (int i = 0; i < 4; ++i)
#pragma unroll
                for (int j = 0; j < 4; ++j) {
                    acc[i][j] = __builtin_amdgcn_mfma_f32_16x16x32_bf16(ah[i], bh[j], acc[i][j], 0, 0, 0);
                    acc[i][j] = __builtin_amdgcn_mfma_f32_16x16x32_bf16(ah[i], bl[j], acc[i][j], 0, 0, 0);
                    acc[i][j] = __builtin_amdgcn_mfma_f32_16x16x32_bf16(al[i], bh[j], acc[i][j], 0, 0, 0);
                }
        }
    }

#pragma unroll
    for (int j = 0; j < 4; ++j) {
        int n = n0 + nsub + j * 16 + lrow;
        float bv = bias[n];
#pragma unroll
        for (int i = 0; i < 4; ++i)
#pragma unroll
            for (int r = 0; r < 4; ++r) {
                int m = m0 + msub + i * 16 + quad * 4 + r;
                C[(size_t)m * 2048 + n] = (f16)(acc[i][j][r] + bv);
            }
    }
}

// ---------------------------------------------------------------------------
// Layer-2 GEMM (R11-verified): A bf16-HI-ONLY, W hi+lo -> 2 MFMA products.
// Dead-tile skip (R13).
__global__ __launch_bounds__(256) void gemm_l2(
    const f16* __restrict__ A, const float* __restrict__ W,
    const float* __restrict__ bias, const int* __restrict__ lengths,
    f16* __restrict__ C) {
    const int m0 = blockIdx.x * 128;
    if ((m0 & 255) >= lengths[m0 >> 8]) return;  // fully-dead tile

    __shared__ bf16 Ah[128][72];
    __shared__ bf16 Wh[128][72], Wl[128][72];
    const int n0 = blockIdx.y * 128;
    const int tid = threadIdx.x;
    const int wave = tid >> 6;
    const int lane = tid & 63;
    const int lrow = lane & 15;
    const int quad = lane >> 4;
    const int msub = (wave >> 1) * 64;
    const int nsub = (wave & 1) * 64;

    f32x4 acc[4][4];
#pragma unroll
    for (int i = 0; i < 4; ++i)
#pragma unroll
        for (int j = 0; j < 4; ++j) acc[i][j] = (f32x4){0.f, 0.f, 0.f, 0.f};

    for (int k0 = 0; k0 < 1024; k0 += 64) {
        __syncthreads();
#pragma unroll
        for (int c = 0; c < 4; ++c) {
            int f = c * 256 + tid;
            int row = f >> 3;
            int kc = f & 7;
            cvt8h(A + (size_t)(m0 + row) * 1024 + k0 + kc * 8, &Ah[row][kc * 8]);
            split8(W + (size_t)(n0 + row) * 1024 + k0 + kc * 8,
                   &Wh[row][kc * 8], &Wl[row][kc * 8]);
        }
        __syncthreads();
#pragma unroll
        for (int ks = 0; ks < 2; ++ks) {
            short8 ah[4], bh[4], bl[4];
#pragma unroll
            for (int i = 0; i < 4; ++i)
                ah[i] = *(const short8*)&Ah[msub + i * 16 + lrow][ks * 32 + quad * 8];
#pragma unroll
            for (int j = 0; j < 4; ++j) {
                bh[j] = *(const short8*)&Wh[nsub + j * 16 + lrow][ks * 32 + quad * 8];
                bl[j] = *(const short8*)&Wl[nsub + j * 16 + lrow][ks * 32 + quad * 8];
            }
#pragma unroll
            for (int i = 0; i < 4; ++i)
#pragma unroll
                for (int j = 0; j < 4; ++j) {
                    acc[i][j] = __builtin_amdgcn_mfma_f32_16x16x32_bf16(ah[i], bh[j], acc[i][j], 0, 0, 0);
                    acc[i][j] = __builtin_amdgcn_mfma_f32_16x16x32_bf16(ah[i], bl[j], acc[i][j], 0, 0, 0);
                }
        }
    }

#pragma unroll
    for (int j = 0; j < 4; ++j) {
        int n = n0 + nsub + j * 16 + lrow;
        float bv = bias[n];
#pragma unroll
        for (int i = 0; i < 4; ++i)
#pragma unroll
            for (int r = 0; r < 4; ++r) {
                int m = m0 + msub + i * 16 + quad * 4 + r;
                C[(size_t)m * 2048 + n] = (f16)(acc[i][j][r] + bv);
            }
    }
}

// ---------------------------------------------------------------------------
// Classifier (R13-exact): dead-tile bias fast path + 3-product core.
__global__ __launch_bounds__(256) void cls_gemm(
    const f16* __restrict__ A, const float* __restrict__ W,
    const float* __restrict__ bias, const int* __restrict__ lengths,
    float* __restrict__ C) {
    const int m0 = blockIdx.x * 128;
    const int tid = threadIdx.x;
    if ((m0 & 255) >= lengths[m0 >> 8]) {
        for (int f = tid; f < 128 * NTAGS; f += 256) {
            int r = f / NTAGS, n = f % NTAGS;
            C[(size_t)(m0 + r) * NTAGS + n] = bias[n];
        }
        return;
    }

    __shared__ bf16 Ah[128][72], Al[128][72];
    __shared__ bf16 Wh[64][72], Wl[64][72];
    const int wave = tid >> 6;
    const int lane = tid & 63;
    const int lrow = lane & 15;
    const int quad = lane >> 4;
    const int msub = wave * 32;

    f32x4 acc[2][4];
#pragma unroll
    for (int i = 0; i < 2; ++i)
#pragma unroll
        for (int j = 0; j < 4; ++j) acc[i][j] = (f32x4){0.f, 0.f, 0.f, 0.f};

    for (int k0 = 0; k0 < 1024; k0 += 64) {
        __syncthreads();
#pragma unroll
        for (int c = 0; c < 4; ++c) {
            int f = c * 256 + tid;
            int row = f >> 3;
            int kc = f & 7;
            split8h(A + (size_t)(m0 + row) * 1024 + k0 + kc * 8,
                    &Ah[row][kc * 8], &Al[row][kc * 8]);
        }
#pragma unroll
        for (int c = 0; c < 2; ++c) {
            int f = c * 256 + tid;
            int row = f >> 3;
            int kc = f & 7;
            int wr = row < NTAGS ? row : NTAGS - 1;
            split8(W + (size_t)wr * 1024 + k0 + kc * 8,
                   &Wh[row][kc * 8], &Wl[row][kc * 8]);
        }
        __syncthreads();
#pragma unroll
        for (int ks = 0; ks < 2; ++ks) {
            short8 ah[2], al[2], bh[4], bl[4];
#pragma unroll
            for (int i = 0; i < 2; ++i) {
                ah[i] = *(const short8*)&Ah[msub + i * 16 + lrow][ks * 32 + quad * 8];
                al[i] = *(const short8*)&Al[msub + i * 16 + lrow][ks * 32 + quad * 8];
            }
#pragma unroll
            for (int j = 0; j < 4; ++j) {
                bh[j] = *(const short8*)&Wh[j * 16 + lrow][ks * 32 + quad * 8];
                bl[j] = *(const short8*)&Wl[j * 16 + lrow][ks * 32 + quad * 8];
            }
#pragma unroll
            for (int i = 0; i < 2; ++i)
#pragma unroll
                for (int j = 0; j < 4; ++j) {
                    acc[i][j] = __builtin_amdgcn_mfma_f32_16x16x32_bf16(ah[i], bh[j], acc[i][j], 0, 0, 0);
                    acc[i][j] = __builtin_amdgcn_mfma_f32_16x16x32_bf16(ah[i], bl[j], acc[i][j], 0, 0, 0);
                    acc[i][j] = __builtin_amdgcn_mfma_f32_16x16x32_bf16(al[i], bh[j], acc[i][j], 0, 0, 0);
                }
        }
    }

#pragma unroll
    for (int j = 0; j < 4; ++j) {
        int n = j * 16 + lrow;
        if (n < NTAGS) {
            float bv = bias[n];
#pragma unroll
            for (int i = 0; i < 2; ++i)
#pragma unroll
                for (int r = 0; r < 4; ++r) {
                    int m = m0 + msub + i * 16 + quad * 4 + r;
                    C[(size_t)m * NTAGS + n] = acc[i][j][r] + bv;
                }
        }
    }
}

// ---------------------------------------------------------------------------
// Persistent masked BiLSTM scan — R13 wave-autonomous protocol (verified,
// ~980us/scan) + TRANSPOSED hbuf: [dir][parity][slab=sl][batch][8 units].
//
// RESUBMISSION of R14 (container failed twice with no timing block — same
// infra signature as R6/R7, which a byte-near resubmit disproved in R8).
// Delta audit vs verified R13: pure address-map change.
//   producer: offset gb*16 + u0*2 == wave*256 + lane*4  (one coalesced
//   256-B wave store, was 16 scattered lines)
//   consumer: unit c*32+quad*8+j -> slab c*4+quad, addr hpb +
//   (c*4+quad)*1024 + b*16  (same 16x16B loads)
// Flags/poll/parity induction byte-identical to R13; wrong addresses would
// fail absmax, not hang — no hang mechanism in the delta.
__global__ __launch_bounds__(256, 1) void lstm_scan(
    const f16* __restrict__ xpre_f, const f16* __restrict__ xpre_b,
    const float* __restrict__ whh_f, const float* __restrict__ whh_b,
    const int* __restrict__ lengths,
    f16* __restrict__ out,      // [BT, 2H]
    bf16* __restrict__ hbuf,    // [dir][parity][slab][batch][8] (transposed)
    int* __restrict__ bar, int base) {
    __shared__ bf16 w_lo2[32][64][8];  // [slot=nt*16+c][lane][8] : lane-private
    __shared__ float gat[64][33];      // [batch][gate*8+u], stride 33
    __shared__ int len_s[64];

    const int dir = blockIdx.x >> 6;
    const int sl = blockIdx.x & 63;
    const int tid = threadIdx.x;
    const int wave = tid >> 6;
    const int lane = tid & 63;
    const int lrow = lane & 15;
    const int quad = lane >> 4;
    // wave-local gate mapping: thread -> (batch gb in wave's 16, unit-pair)
    const int gb = wave * 16 + (lane >> 2);
    const int up = lane & 3;
    const int u0 = up * 2;

    const f16* xpre = dir ? xpre_b : xpre_f;
    const float* whh = dir ? whh_b : whh_f;
    // per-dir region: 2 parities x 64 slabs x 64 batches x 16 B = 128 KB
    char* hb = (char*)hbuf + (size_t)dir * 131072;
    int* flags = bar + dir * 8192;             // 512 flags, 64B apart
    int* myflag = flags + (wave * 64 + sl) * 16;
    int* pollp = flags + (wave * 64 + lane) * 16;

    // ---- stage w_hh slice: hi -> regs BH[nt][c], lo -> lane-private LDS.
    short8 BH[2][16];
#pragma unroll
    for (int nt = 0; nt < 2; ++nt) {
        int R = nt * 16 + lrow;
        const float* wr = whh + (size_t)((R >> 3) * HH + sl * 8 + (R & 7)) * HH + quad * 8;
#pragma unroll
        for (int c = 0; c < 16; ++c) {
            float4 v0 = *(const float4*)(wr + c * 32);
            float4 v1 = *(const float4*)(wr + c * 32 + 4);
            float vv[8] = {v0.x, v0.y, v0.z, v0.w, v1.x, v1.y, v1.z, v1.w};
            short8 h8, l8;
#pragma unroll
            for (int j = 0; j < 8; ++j) {
                bf16 h = __float2bfloat16(vv[j]);
                h8[j] = (short)__bfloat16_as_ushort(h);
                l8[j] = f2bs(vv[j] - __bfloat162float(h));
            }
            BH[nt][c] = h8;
            *(short8*)&w_lo2[nt * 16 + c][lane][0] = l8;
        }
    }
    if (tid < 64) len_s[tid] = lengths[tid];
    __syncthreads();   // init barrier only (w_lo2/len_s visible to all)

    // persistent per-thread recurrent state (2 hidden units each)
    float hr0 = 0.f, hr1 = 0.f, cr0 = 0.f, cr1 = 0.f;

    // prefetch xpre for s = 0 (len >= 1 always)
    float pr[2][4];
    {
        int len = len_s[gb];
        int ta = dir ? (len - 1) : 0;
        const f16* xp = xpre + (size_t)(gb * TT + ta) * 2048 + sl * 8 + u0;
        half2v g0 = *(const half2v*)(xp);
        half2v g1 = *(const half2v*)(xp + 512);
        half2v g2 = *(const half2v*)(xp + 1024);
        half2v g3 = *(const half2v*)(xp + 1536);
        pr[0][0] = (float)g0[0]; pr[1][0] = (float)g0[1];
        pr[0][1] = (float)g1[0]; pr[1][1] = (float)g1[1];
        pr[0][2] = (float)g2[0]; pr[1][2] = (float)g2[1];
        pr[0][3] = (float)g3[0]; pr[1][3] = (float)g3[1];
    }

    for (int s = 0; s < TT; ++s) {
        if (s > 0) {
            const int target = base + s;

            // ---- per-wave readiness poll of its OWN dependency group
            {
                int v = __hip_atomic_load(pollp, __ATOMIC_RELAXED,
                                          __HIP_MEMORY_SCOPE_AGENT);
                while (__ballot(v >= target) != ~0ull) {
                    __builtin_amdgcn_s_sleep(1);
                    v = __hip_atomic_load(pollp, __ATOMIC_RELAXED,
                                          __HIP_MEMORY_SCOPE_AGENT);
                }
            }
            __asm__ volatile("" ::: "memory");

            // ---- burst-issue this wave's h fragments: 16 x dwordx4, sc0 sc1
            // AH[c] = units [c*32+quad*8, +8) of batch b  ->  transposed addr
            // hpb + (c*4+quad)*1024 + b*16
            const int b = wave * 16 + lrow;
            const char* hpb = hb + (size_t)((s & 1) ^ 1) * 65536;
            const char* hib = hpb + quad * 1024 + b * 16;

            short8 AH[16];
#pragma unroll
            for (int c = 0; c < 16; ++c) {
                asm volatile("global_load_dwordx4 %0, %1, off sc0 sc1"
                             : "=v"(AH[c]) : "v"(hib + c * 4096));
            }

            // 8 accumulator chains: (nt, c&3); staged vmcnt 12/8/4/0
            f32x4 ac[2][4];
#pragma unroll
            for (int nt = 0; nt < 2; ++nt)
#pragma unroll
                for (int q = 0; q < 4; ++q)
                    ac[nt][q] = (f32x4){0.f, 0.f, 0.f, 0.f};

            asm volatile("s_waitcnt vmcnt(12)" ::: "memory");
            __builtin_amdgcn_sched_barrier(0);
#pragma unroll
            for (int c = 0; c < 4; ++c)
#pragma unroll
                for (int nt = 0; nt < 2; ++nt) {
                    short8 bll = *(const short8*)&w_lo2[nt * 16 + c][lane][0];
                    ac[nt][c & 3] = __builtin_amdgcn_mfma_f32_16x16x32_bf16(AH[c], BH[nt][c], ac[nt][c & 3], 0, 0, 0);
                    ac[nt][c & 3] = __builtin_amdgcn_mfma_f32_16x16x32_bf16(AH[c], bll, ac[nt][c & 3], 0, 0, 0);
                }
            asm volatile("s_waitcnt vmcnt(8)" ::: "memory");
            __builtin_amdgcn_sched_barrier(0);
#pragma unroll
            for (int c = 4; c < 8; ++c)
#pragma unroll
                for (int nt = 0; nt < 2; ++nt) {
                    short8 bll = *(const short8*)&w_lo2[nt * 16 + c][lane][0];
                    ac[nt][c & 3] = __builtin_amdgcn_mfma_f32_16x16x32_bf16(AH[c], BH[nt][c], ac[nt][c & 3], 0, 0, 0);
                    ac[nt][c & 3] = __builtin_amdgcn_mfma_f32_16x16x32_bf16(AH[c], bll, ac[nt][c & 3], 0, 0, 0);
                }
            asm volatile("s_waitcnt vmcnt(4)" ::: "memory");
            __builtin_amdgcn_sched_barrier(0);
#pragma unroll
            for (int c = 8; c < 12; ++c)
#pragma unroll
                for (int nt = 0; nt < 2; ++nt) {
                    short8 bll = *(const short8*)&w_lo2[nt * 16 + c][lane][0];
                    ac[nt][c & 3] = __builtin_amdgcn_mfma_f32_16x16x32_bf16(AH[c], BH[nt][c], ac[nt][c & 3], 0, 0, 0);
                    ac[nt][c & 3] = __builtin_amdgcn_mfma_f32_16x16x32_bf16(AH[c], bll, ac[nt][c & 3], 0, 0, 0);
                }
            asm volatile("s_waitcnt vmcnt(0)" ::: "memory");
            __builtin_amdgcn_sched_barrier(0);
#pragma unroll
            for (int c = 12; c < 16; ++c)
#pragma unroll
                for (int nt = 0; nt < 2; ++nt) {
                    short8 bll = *(const short8*)&w_lo2[nt * 16 + c][lane][0];
                    ac[nt][c & 3] = __builtin_amdgcn_mfma_f32_16x16x32_bf16(AH[c], BH[nt][c], ac[nt][c & 3], 0, 0, 0);
                    ac[nt][c & 3] = __builtin_amdgcn_mfma_f32_16x16x32_bf16(AH[c], bll, ac[nt][c & 3], 0, 0, 0);
                }
            // acc -> gat (wave-local rows only); rule #18 fence, no barrier.
#pragma unroll
            for (int nt = 0; nt < 2; ++nt)
#pragma unroll
                for (int r = 0; r < 4; ++r)
                    gat[wave * 16 + quad * 4 + r][nt * 16 + lrow] =
                        (ac[nt][0][r] + ac[nt][1][r]) + (ac[nt][2][r] + ac[nt][3][r]);
            asm volatile("s_waitcnt lgkmcnt(0)" ::: "memory");
            __builtin_amdgcn_sched_barrier(0);
        }

        // ---- gate phase: thread handles (gb, units u0,u0+1), wave-local ----
        const int len = len_s[gb];
        const bool act = (s < len);
        if (act) {
            float z0[4], z1[4];
#pragma unroll
            for (int g = 0; g < 4; ++g) { z0[g] = pr[0][g]; z1[g] = pr[1][g]; }
            if (s > 0) {
#pragma unroll
                for (int g = 0; g < 4; ++g) {
                    z0[g] += gat[gb][g * 8 + u0];
                    z1[g] += gat[gb][g * 8 + u0 + 1];
                }
            }
            float i0 = sigm(z0[0]), f0 = sigm(z0[1]);
            float g0 = tanh_f(z0[2]), o0 = sigm(z0[3]);
            float i1 = sigm(z1[0]), f1 = sigm(z1[1]);
            float g1 = tanh_f(z1[2]), o1 = sigm(z1[3]);
            cr0 = f0 * cr0 + i0 * g0;
            cr1 = f1 * cr1 + i1 * g1;
            hr0 = o0 * tanh_f(cr0);
            hr1 = o1 * tanh_f(cr1);
        }
        // publish h-hi packed (always; carried h for masked rows):
        // transposed layout -> hcb + sl*1024 + wave*256 + lane*4 =
        // ONE coalesced 256-B store per wave.
        {
            bf16 bh0 = __float2bfloat16(hr0);
            bf16 bh1 = __float2bfloat16(hr1);
            unsigned int hw = (unsigned int)__bfloat16_as_ushort(bh0) |
                              ((unsigned int)__bfloat16_as_ushort(bh1) << 16);
            char* hcb = hb + (size_t)(s & 1) * 65536;
            char* pa = hcb + sl * 1024 + wave * 256 + lane * 4;
            asm volatile("global_store_dword %0, %1, off sc0 sc1"
                         :: "v"(pa), "v"(hw) : "memory");
        }
        // per-wave drain, then this wave's flag — NO block barrier
        asm volatile("s_waitcnt vmcnt(0)" ::: "memory");
        if (lane == 0)
            __hip_atomic_store(myflag, base + s + 1, __ATOMIC_RELAXED,
                               __HIP_MEMORY_SCOPE_AGENT);

        // off the inter-wave critical path: prefetch next xpre, then out store
        if (s + 1 < TT) {
            if (s + 1 < len) {
                int ta = dir ? (len - 2 - s) : (s + 1);
                const f16* xp = xpre + (size_t)(gb * TT + ta) * 2048 + sl * 8 + u0;
                half2v g0 = *(const half2v*)(xp);
                half2v g1 = *(const half2v*)(xp + 512);
                half2v g2 = *(const half2v*)(xp + 1024);
                half2v g3 = *(const half2v*)(xp + 1536);
                pr[0][0] = (float)g0[0]; pr[1][0] = (float)g0[1];
                pr[0][1] = (float)g1[0]; pr[1][1] = (float)g1[1];
                pr[0][2] = (float)g2[0]; pr[1][2] = (float)g2[1];
                pr[0][3] = (float)g3[0]; pr[1][3] = (float)g3[1];
            }
        }
        if (act) {
            int ta = dir ? (len - 1 - s) : s;
            half2v ov; ov[0] = (f16)hr0; ov[1] = (f16)hr1;
            *(half2v*)(out + (size_t)(gb * TT + ta) * 1024 + dir * 512 + sl * 8 + u0) = ov;
        } else {
            half2v zv; zv[0] = (f16)0.f; zv[1] = (f16)0.f;
            *(half2v*)(out + (size_t)(gb * TT + s) * 1024 + dir * 512 + sl * 8 + u0) = zv;
        }
    }
}

// ---------------------------------------------------------------------------
extern "C" void kernel_launch(void* const* d_in, const int* in_sizes, int n_in,
                              void* d_out, int out_size, void* d_ws, size_t ws_size,
                              hipStream_t stream) {
    const int* x = (const int*)d_in[0];
    const int* lengths = (const int*)d_in[1];
    const float* emb = (const float*)d_in[2];
    const float* w_ih_f1 = (const float*)d_in[3];
    const float* w_hh_f1 = (const float*)d_in[4];
    const float* b_f1 = (const float*)d_in[5];
    const float* w_ih_b1 = (const float*)d_in[6];
    const float* w_hh_b1 = (const float*)d_in[7];
    const float* b_b1 = (const float*)d_in[8];
    const float* w_ih_f2 = (const float*)d_in[9];
    const float* w_hh_f2 = (const float*)d_in[10];
    const float* b_f2 = (const float*)d_in[11];
    const float* w_ih_b2 = (const float*)d_in[12];
    const float* w_hh_b2 = (const float*)d_in[13];
    const float* b_b2 = (const float*)d_in[14];
    const float* cls_w = (const float*)d_in[15];
    const float* cls_b = (const float*)d_in[16];
    float* logits = (float*)d_out;

    // workspace layout (bytes) — max touched offset ~176 MB (proven envelope)
    char* ws = (char*)d_ws;
    int* bar = (int*)ws;                        // 0 .. 64 KB (2x512 flags, 64B apart)
    bf16* hbuf = (bf16*)(ws + 65536);           // 64 KB .. 320 KB (transposed)
    f16* xpre_f = (f16*)(ws + 16777216);        // 16 MB .. 80 MB
    f16* xpre_b = (f16*)(ws + 83886080);        // 80 MB .. 144 MB
    f16* out1 = (f16*)(ws + 150994944);         // 144 MB .. 176 MB
    f16* out2 = out1;  // alias: out1 dead once layer-2 GEMMs complete

    bar_init<<<64, 256, 0, stream>>>(bar);

    dim3 g1(BT / 128, 2048 / 128);
    gemm_emb<<<g1, 256, 0, stream>>>(x, emb, w_ih_f1, b_f1, lengths, xpre_f);
    gemm_emb<<<g1, 256, 0, stream>>>(x, emb, w_ih_b1, b_b1, lengths, xpre_b);
    lstm_scan<<<128, 256, 0, stream>>>(xpre_f, xpre_b, w_hh_f1, w_hh_b1,
                                       lengths, out1, hbuf, bar, 0);

    gemm_l2<<<g1, 256, 0, stream>>>(out1, w_ih_f2, b_f2, lengths, xpre_f);
    gemm_l2<<<g1, 256, 0, stream>>>(out1, w_ih_b2, b_b2, lengths, xpre_b);
    lstm_scan<<<128, 256, 0, stream>>>(xpre_f, xpre_b, w_hh_f2, w_hh_b2,
                                       lengths, out2, hbuf, bar, TT);

    cls_gemm<<<BT / 128, 256, 0, stream>>>(out2, cls_w, cls_b, lengths, logits);
}